// Round 9
// baseline (413.433 us; speedup 1.0000x reference)
//
#include <hip/hip_runtime.h>

#define TT 512
#define BB 1024
#define INV2PI 0.15915494309189535f
#define INV4PI 0.07957747154594767f

__device__ __forceinline__ float frcp(float x){ return __builtin_amdgcn_rcpf(x); }
// cos(2*pi*r) with r in revolutions; exact fract reduction + V_COS
__device__ __forceinline__ float fcosrev(float r){
  float rr = r - floorf(r);
  return __builtin_amdgcn_cosf(rr);
}

// tanh(y) odd degree-13 Taylor, |y|<=1 (err <=1.1e-3 at |y|=1)
__device__ __forceinline__ float tanh13(float y){
  float s = y*y;
  float p = fmaf(s, 0.00359213f, -0.00886324f);
  p = fmaf(p, s, 0.02186948f);
  p = fmaf(p, s, -0.05396825f);
  p = fmaf(p, s, 0.13333333f);
  p = fmaf(p, s, -0.33333333f);
  p = fmaf(p, s, 1.0f);
  return y*p;
}

// DPP helpers (controls validated R3-R8 by passing runs).
#define DPPZ(v, ctrl) __int_as_float(__builtin_amdgcn_update_dpp(0, __float_as_int(v), (ctrl), 0xF, 0xF, true))
#define DPPR(v, ctrl) __int_as_float(__builtin_amdgcn_update_dpp(__float_as_int(v), __float_as_int(v), (ctrl), 0xF, 0xF, false))

// ---------------- Phase 1: xpre projection (pre-scaled to revolutions) ----
__global__ __launch_bounds__(256,1) void qlstm_proj(
    const float* __restrict__ x,
    const float* __restrict__ Wf, const float* __restrict__ bf, const float* __restrict__ thf,
    const float* __restrict__ Wi, const float* __restrict__ bi, const float* __restrict__ thi,
    const float* __restrict__ Wu, const float* __restrict__ bu, const float* __restrict__ thu,
    const float* __restrict__ Wo, const float* __restrict__ bo, const float* __restrict__ tho,
    const float* __restrict__ bh2k,
    const float* __restrict__ Wi2k, const float* __restrict__ bi2k,
    float* __restrict__ buf)
{
  __shared__ float4 wl4[64][10];
  __shared__ float bias[40];
  int tid = threadIdx.x;
  float* wl = (float*)wl4;
  for (int idx = tid; idx < 64*40; idx += 256){
    int d = idx / 40, c = idx - d*40;
    float v;
    if (c < 32){
      int g = c >> 3, jj = c & 7;
      const float* W = (g==0)?Wf:((g==1)?Wi:((g==2)?Wu:Wo));
      v = W[d*8+jj] * INV2PI;
    } else {
      v = Wi2k[d*8 + (c-32)] * INV4PI;
    }
    wl[d*40+c] = v;
  }
  if (tid < 40){
    int c = tid; float v;
    if (c < 32){
      int g = c >> 3, jj = c & 7;
      const float* bp = (g==0)?bf:((g==1)?bi:((g==2)?bu:bo));
      const float* tp = (g==0)?thf:((g==1)?thi:((g==2)?thu:tho));
      v = (bp[jj] + tp[jj]) * INV2PI;
    } else {
      v = (bi2k[c-32] - bh2k[c-32]) * INV4PI;
    }
    bias[c] = v;
  }
  __syncthreads();

  int ch = tid >> 7;               // column half (wave-uniform)
  int rt = tid & 127;
  long r0 = (long)blockIdx.x*1024 + (long)rt*8;   // 8 consecutive rows
  const float4* xp = (const float4*)(x + r0*64);
  int qb = ch*5;

  float4 acc[8][5];
#pragma unroll
  for (int r=0;r<8;++r)
#pragma unroll
    for (int q=0;q<5;++q){
      int c4 = (qb+q)*4;
      acc[r][q] = make_float4(bias[c4],bias[c4+1],bias[c4+2],bias[c4+3]);
    }

#pragma unroll 1
  for (int d4=0; d4<16; ++d4){
    float4 xv[8];
#pragma unroll
    for (int r=0;r<8;++r) xv[r] = xp[r*16 + d4];
#pragma unroll
    for (int dd=0; dd<4; ++dd){
#pragma unroll
      for (int q=0;q<5;++q){
        float4 wv = wl4[d4*4+dd][qb+q];
#pragma unroll
        for (int r=0;r<8;++r){
          float sc = (dd==0)?xv[r].x:((dd==1)?xv[r].y:((dd==2)?xv[r].z:xv[r].w));
          acc[r][q].x += sc*wv.x; acc[r][q].y += sc*wv.y;
          acc[r][q].z += sc*wv.z; acc[r][q].w += sc*wv.w;
        }
      }
    }
  }

#pragma unroll
  for (int r=0;r<8;++r){
    float4* ob = (float4*)(buf + (r0+r)*40 + qb*4);
#pragma unroll
    for (int q=0;q<5;++q) ob[q] = acc[r][q];
  }
}

// ---------------- Phase 2: scan, ILP-2 -------------------------------------
// 16-lane group handles TWO batch elements (b0, b0+1) in one interleaved
// instruction stream -> dependent-latency stalls of one chain are filled by
// the other chain's instructions. Weights shared across the pair.
// lane bits: j=bits0-2, p=bit3 (pair: 0->{f,i}, 1->{u,o}), group=bits4-5.
// kv is computed split: pb=0 lanes handle elem0's kernel product, pb=1 elem1's,
// exchanged via ror:8. Store merged: pb=0 lanes store elem0 h, pb=1 elem1 h.
__global__ __launch_bounds__(64,1) void qlstm_scan(
    const float* __restrict__ buf,
    const float* __restrict__ Wf, const float* __restrict__ Wi,
    const float* __restrict__ Wu, const float* __restrict__ Wo,
    const float* __restrict__ Wh2k,
    float* __restrict__ out,
    float* __restrict__ hstate, float* __restrict__ cstate,
    int t0, int tc, int initf, int lastf)
{
  int tid = threadIdx.x;          // 64
  int j = tid & 7;
  bool pb = (tid & 8) != 0;       // gate-pair select
  bool j4 = (j & 4) != 0;
  int b0 = blockIdx.x*8 + ((tid >> 4) << 1);   // even element of the pair

  // slot A: p=0 -> f (sigmoid), p=1 -> u (tanh) ; slot B: i / o (sigmoid)
  const float* WA = pb ? Wu : Wf;
  const float* WB = pb ? Wo : Wi;
#define LDW(S_) \
  float wA##S_ = WA[(64+((j+S_)&7))*8 + j] * INV2PI; \
  float wB##S_ = WB[(64+((j+S_)&7))*8 + j] * INV2PI; \
  float wK##S_ = Wh2k[((j+S_)&7)*8 + j] * INV4PI;
  LDW(0) LDW(1) LDW(2) LDW(3) LDW(4) LDW(5) LDW(6) LDW(7)
#undef LDW

  float preY  = pb ? 1.0f : 0.5f;
  float postM = pb ? 1.0f : 0.5f;
  float postB = pb ? 0.0f : 0.5f;

  float h0, c0, h1, c1;
  if (initf){ h0=0.f; c0=0.f; h1=0.f; c1=0.f; }
  else {
    h0 = hstate[b0*8+j];     c0 = cstate[b0*8+j];
    h1 = hstate[(b0+1)*8+j]; c1 = cstate[(b0+1)*8+j];
  }

  const int S = BB*40;              // per-step stride (floats)
  int oA0 = b0*40 + (pb?16:0) + j;  // elem0 gate-A pre
  int oA1 = oA0 + 40;               // elem1 gate-A pre
  int oKs = b0*40 + 32 + j + (pb?40:0);  // OWN element's kernel pre (split)

  float xA0q[4], xB0q[4], xA1q[4], xB1q[4], xKq[4];
#pragma unroll
  for (int i=0;i<4;++i){
    xA0q[i]=buf[oA0 + i*S];   xB0q[i]=buf[oA0 + 8 + i*S];
    xA1q[i]=buf[oA1 + i*S];   xB1q[i]=buf[oA1 + 8 + i*S];
    xKq[i] =buf[oKs + i*S];
  }
  int offA0 = oA0 + 4*S;            // unconditional cursors (buf padded +8 rows)
  int offA1 = oA1 + 4*S;
  int offK  = oKs + 4*S;
  int ostv  = (t0*BB + b0 + (pb?1:0))*8 + j;   // merged output cursor

  for (int tt4 = 0; tt4 < tc; tt4 += 4){
#pragma unroll
    for (int u=0; u<4; ++u){
      float xA0=xA0q[u], xB0=xB0q[u], xA1=xA1q[u], xB1=xB1q[u], xK=xKq[u];
      xA0q[u]=buf[offA0]; xB0q[u]=buf[offA0+8];
      xA1q[u]=buf[offA1]; xB1q[u]=buf[offA1+8];
      xKq[u] =buf[offK];
      offA0 += S; offA1 += S; offK += S;

      // rotations (rotate-left-by-s within 16-row), both elements
      float p0r1=DPPR(h0,0x12F), p0r2=DPPR(h0,0x12E), p0r3=DPPR(h0,0x12D),
            p0r4=DPPR(h0,0x12C), p0r5=DPPR(h0,0x12B), p0r6=DPPR(h0,0x12A),
            p0r7=DPPR(h0,0x129);
      float p1r1=DPPR(h1,0x12F), p1r2=DPPR(h1,0x12E), p1r3=DPPR(h1,0x12D),
            p1r4=DPPR(h1,0x12C), p1r5=DPPR(h1,0x12B), p1r6=DPPR(h1,0x12A),
            p1r7=DPPR(h1,0x129);

      // matvecs, 2-accumulator trees, both elements
      float aA0a =      h0*wA0;  aA0a=fmaf(p0r2,wA2,aA0a); aA0a=fmaf(p0r4,wA4,aA0a); aA0a=fmaf(p0r6,wA6,aA0a);
      float aA0b =    p0r1*wA1;  aA0b=fmaf(p0r3,wA3,aA0b); aA0b=fmaf(p0r5,wA5,aA0b); aA0b=fmaf(p0r7,wA7,aA0b);
      float aA0 = aA0a + aA0b;
      float aB0a =      h0*wB0;  aB0a=fmaf(p0r2,wB2,aB0a); aB0a=fmaf(p0r4,wB4,aB0a); aB0a=fmaf(p0r6,wB6,aB0a);
      float aB0b =    p0r1*wB1;  aB0b=fmaf(p0r3,wB3,aB0b); aB0b=fmaf(p0r5,wB5,aB0b); aB0b=fmaf(p0r7,wB7,aB0b);
      float aB0 = aB0a + aB0b;
      float aK0a =      h0*wK0;  aK0a=fmaf(p0r2,wK2,aK0a); aK0a=fmaf(p0r4,wK4,aK0a); aK0a=fmaf(p0r6,wK6,aK0a);
      float aK0b =    p0r1*wK1;  aK0b=fmaf(p0r3,wK3,aK0b); aK0b=fmaf(p0r5,wK5,aK0b); aK0b=fmaf(p0r7,wK7,aK0b);
      float aK0 = aK0a + aK0b;
      float aA1a =      h1*wA0;  aA1a=fmaf(p1r2,wA2,aA1a); aA1a=fmaf(p1r4,wA4,aA1a); aA1a=fmaf(p1r6,wA6,aA1a);
      float aA1b =    p1r1*wA1;  aA1b=fmaf(p1r3,wA3,aA1b); aA1b=fmaf(p1r5,wA5,aA1b); aA1b=fmaf(p1r7,wA7,aA1b);
      float aA1 = aA1a + aA1b;
      float aB1a =      h1*wB0;  aB1a=fmaf(p1r2,wB2,aB1a); aB1a=fmaf(p1r4,wB4,aB1a); aB1a=fmaf(p1r6,wB6,aB1a);
      float aB1b =    p1r1*wB1;  aB1b=fmaf(p1r3,wB3,aB1b); aB1b=fmaf(p1r5,wB5,aB1b); aB1b=fmaf(p1r7,wB7,aB1b);
      float aB1 = aB1a + aB1b;
      float aK1a =      h1*wK0;  aK1a=fmaf(p1r2,wK2,aK1a); aK1a=fmaf(p1r4,wK4,aK1a); aK1a=fmaf(p1r6,wK6,aK1a);
      float aK1b =    p1r1*wK1;  aK1b=fmaf(p1r3,wK3,aK1b); aK1b=fmaf(p1r5,wK5,aK1b); aK1b=fmaf(p1r7,wK7,aK1b);
      float aK1 = aK1a + aK1b;

      // kernel weight, split across pb halves: own element's product, then swap
      float aKsel = pb ? aK1 : aK0;
      float kv = fcosrev(aKsel - xK);
      kv *= DPPR(kv,0xB1);                       // xor1
      kv *= DPPR(kv,0x4E);                       // xor2
      { float t4a = DPPR(kv,0x124), t4b = DPPR(kv,0x12C);
        kv *= (j4 ? t4a : t4b); }                // xor4 (stays inside 8-group)
      float wko = fabsf(kv);
      float wkx = DPPR(wko,0x128);               // other half's value
      float wk0 = pb ? wkx : wko;
      float wk1 = pb ? wko : wkx;

      // masked cumprod qlayer (masks guard 16-row edge AND lane-8 group edge)
#define CUMQ(ZV, WK, GQ) { \
      float zz = (ZV); \
      float pz = zz, s_; \
      s_ = DPPZ(pz,0x111); pz *= ((j>=1)? s_ : 1.0f); \
      s_ = DPPZ(pz,0x112); pz *= ((j>=2)? s_ : 1.0f); \
      s_ = DPPZ(pz,0x114); pz *= ((j>=4)? s_ : 1.0f); \
      float q = (j==0)? 1.0f : zz; \
      q *= DPPR(q,0xB1); \
      q *= DPPR(q,0x4E); \
      { float q4a = DPPR(q,0x124), q4b = DPPR(q,0x12C); q *= (j4 ? q4a : q4b); } \
      GQ = ((j==0)? q : pz) * (WK); }

      float gA0, gB0, gA1, gB1;
      CUMQ(fcosrev(aA0 + xA0), wk0, gA0)
      CUMQ(fcosrev(aB0 + xB0), wk0, gB0)
      CUMQ(fcosrev(aA1 + xA1), wk1, gA1)
      CUMQ(fcosrev(aB1 + xB1), wk1, gB1)
#undef CUMQ

      // activations
      float tA0 = tanh13(gA0 * preY);  float actA0 = fmaf(tA0, postM, postB);
      float tB0 = tanh13(gB0 * 0.5f);  float actB0 = fmaf(tB0, 0.5f, 0.5f);
      float tA1 = tanh13(gA1 * preY);  float actA1 = fmaf(tA1, postM, postB);
      float tB1 = tanh13(gB1 * 0.5f);  float actB1 = fmaf(tB1, 0.5f, 0.5f);

      // cross-pair gather via ror:8
      float gAo0 = DPPR(actA0,0x128), gBo0 = DPPR(actB0,0x128);
      float gAo1 = DPPR(actA1,0x128), gBo1 = DPPR(actB1,0x128);
      float fv0 = pb ? gAo0  : actA0;
      float uv0 = pb ? actA0 : gAo0;
      float iv0 = pb ? gBo0  : actB0;
      float ov0 = pb ? actB0 : gBo0;
      float fv1 = pb ? gAo1  : actA1;
      float uv1 = pb ? actA1 : gAo1;
      float iv1 = pb ? gBo1  : actB1;
      float ov1 = pb ? actB1 : gBo1;

      c0 = fmaf(fv0, c0, iv0*uv0);
      c1 = fmaf(fv1, c1, iv1*uv1);
      // tanh(c) via Pade(5,4)
      float c20 = c0*c0;
      float num0 = fmaf(c20, c20 + 105.0f, 945.0f);
      float den0 = fmaf(c20, fmaf(c20, 15.0f, 420.0f), 945.0f);
      float tch0 = c0 * num0 * frcp(den0);
      h0 = ov0 * tch0;
      float c21 = c1*c1;
      float num1 = fmaf(c21, c21 + 105.0f, 945.0f);
      float den1 = fmaf(c21, fmaf(c21, 15.0f, 420.0f), 945.0f);
      float tch1 = c1 * num1 * frcp(den1);
      h1 = ov1 * tch1;

      // merged store: pb=0 lanes store elem0, pb=1 lanes store elem1
      out[ostv] = pb ? h1 : h0;
      ostv += BB*8;
    }
  }

  if (lastf){
    size_t ob = (size_t)TT*BB*8 + (size_t)(b0 + (pb?1:0))*8 + j;
    out[ob]            = pb ? h1 : h0;
    out[ob + BB*8]     = pb ? c1 : c0;
  } else {
    int sb = (b0 + (pb?1:0))*8 + j;
    hstate[sb] = pb ? h1 : h0;
    cstate[sb] = pb ? c1 : c0;
  }
}

extern "C" void kernel_launch(void* const* d_in, const int* in_sizes, int n_in,
                              void* d_out, int out_size, void* d_ws, size_t ws_size,
                              hipStream_t stream)
{
  const float* x    = (const float*)d_in[0];
  const float* Wf   = (const float*)d_in[1];
  const float* bf   = (const float*)d_in[2];
  const float* thf  = (const float*)d_in[3];
  const float* Wi   = (const float*)d_in[4];
  const float* bi   = (const float*)d_in[5];
  const float* thi  = (const float*)d_in[6];
  const float* Wu   = (const float*)d_in[7];
  const float* bu   = (const float*)d_in[8];
  const float* thu  = (const float*)d_in[9];
  const float* Wo   = (const float*)d_in[10];
  const float* bo   = (const float*)d_in[11];
  const float* tho  = (const float*)d_in[12];
  const float* Wh2k = (const float*)d_in[13];
  const float* bh2k = (const float*)d_in[14];
  const float* Wi2k = (const float*)d_in[15];
  const float* bi2k = (const float*)d_in[16];
  float* out = (float*)d_out;

  // ws layout: hstate[8192 f] | cstate[8192 f] | xpre buf [tc+8][BB][40]
  float* hstate = (float*)d_ws;
  float* cstate = hstate + BB*8;
  float* buf    = cstate + BB*8;
  long long avail = (long long)ws_size - (long long)(2*BB*8*sizeof(float));
  const long long per_step = 40ll*BB*sizeof(float);  // 160 KiB per time step
  int tc = TT;
  while (tc > 4 && (long long)(tc+8)*per_step > avail) tc >>= 1;

  for (int t0 = 0; t0 < TT; t0 += tc){
    int cur = (TT - t0 < tc) ? (TT - t0) : tc;
    qlstm_proj<<<(cur*BB)/1024, 256, 0, stream>>>(
        x + (size_t)t0*BB*64,
        Wf,bf,thf, Wi,bi,thi, Wu,bu,thu, Wo,bo,tho,
        bh2k, Wi2k, bi2k, buf);
    qlstm_scan<<<BB/8, 64, 0, stream>>>(
        buf, Wf, Wi, Wu, Wo, Wh2k, out, hstate, cstate,
        t0, cur, (t0==0)?1:0, (t0+cur>=TT)?1:0);
  }
}

// Round 10
// 307.395 us; speedup vs baseline: 1.3450x; 1.3450x over previous
//
#include <hip/hip_runtime.h>

#define TT 512
#define BB 1024
#define INV2PI 0.15915494309189535f
#define INV4PI 0.07957747154594767f

__device__ __forceinline__ float frcp(float x){ return __builtin_amdgcn_rcpf(x); }
// cos(2*pi*r) with r in revolutions; exact fract reduction + V_COS
__device__ __forceinline__ float fcosrev(float r){
  float rr = r - floorf(r);
  return __builtin_amdgcn_cosf(rr);
}

// tanh(y) odd degree-13 Taylor, |y|<=1 (err <=1.1e-3 at |y|=1)
__device__ __forceinline__ float tanh13(float y){
  float s = y*y;
  float p = fmaf(s, 0.00359213f, -0.00886324f);
  p = fmaf(p, s, 0.02186948f);
  p = fmaf(p, s, -0.05396825f);
  p = fmaf(p, s, 0.13333333f);
  p = fmaf(p, s, -0.33333333f);
  p = fmaf(p, s, 1.0f);
  return y*p;
}

// DPP helpers (controls validated R3-R8 by passing runs).
#define DPPZ(v, ctrl) __int_as_float(__builtin_amdgcn_update_dpp(0, __float_as_int(v), (ctrl), 0xF, 0xF, true))
#define DPPR(v, ctrl) __int_as_float(__builtin_amdgcn_update_dpp(__float_as_int(v), __float_as_int(v), (ctrl), 0xF, 0xF, false))

// Column layout of buf rows (40 floats):
//  c in [0,32): pairIdx = c>>1 (j = pairIdx&7, pb = pairIdx>>3), slot = c&1.
//               gate g = 2*pb + slot  (pb=0: f,i ; pb=1: u,o)
//               value = (x@Wg[:64] + bg + thg) * INV2PI
//  c in [32,40): j = c-32, value = (x@Wi2k + bi2k - bh2k) * INV4PI
// This makes lane (j,pb)'s two gate values an adjacent float2 at col (pb?16:0)+2j.

// ---------------- Phase 1: xpre projection ----------------
// 4 rows x 20 cols per thread; double-buffered x loads; 1024 blocks.
__global__ __launch_bounds__(256,1) void qlstm_proj(
    const float* __restrict__ x,
    const float* __restrict__ Wf, const float* __restrict__ bf, const float* __restrict__ thf,
    const float* __restrict__ Wi, const float* __restrict__ bi, const float* __restrict__ thi,
    const float* __restrict__ Wu, const float* __restrict__ bu, const float* __restrict__ thu,
    const float* __restrict__ Wo, const float* __restrict__ bo, const float* __restrict__ tho,
    const float* __restrict__ bh2k,
    const float* __restrict__ Wi2k, const float* __restrict__ bi2k,
    float* __restrict__ buf)
{
  __shared__ float4 wl4[64][10];
  __shared__ float bias[40];
  int tid = threadIdx.x;
  float* wl = (float*)wl4;
  for (int idx = tid; idx < 64*40; idx += 256){
    int d = idx / 40, c = idx - d*40;
    float v;
    if (c < 32){
      int pi = c >> 1, slot = c & 1;
      int j = pi & 7, pbc = pi >> 3;
      int g = 2*pbc + slot;
      const float* W = (g==0)?Wf:((g==1)?Wi:((g==2)?Wu:Wo));
      v = W[d*8+j] * INV2PI;
    } else {
      v = Wi2k[d*8 + (c-32)] * INV4PI;
    }
    wl[d*40+c] = v;
  }
  if (tid < 40){
    int c = tid; float v;
    if (c < 32){
      int pi = c >> 1, slot = c & 1;
      int j = pi & 7, pbc = pi >> 3;
      int g = 2*pbc + slot;
      const float* bp = (g==0)?bf:((g==1)?bi:((g==2)?bu:bo));
      const float* tp = (g==0)?thf:((g==1)?thi:((g==2)?thu:tho));
      v = (bp[j] + tp[j]) * INV2PI;
    } else {
      v = (bi2k[c-32] - bh2k[c-32]) * INV4PI;
    }
    bias[c] = v;
  }
  __syncthreads();

  int ch = tid >> 7;               // column half (wave-uniform)
  int rt = tid & 127;
  long r0 = (long)blockIdx.x*512 + (long)rt*4;   // 4 consecutive rows
  const float4* xp = (const float4*)(x + r0*64);
  int qb = ch*5;

  float4 acc[4][5];
#pragma unroll
  for (int r=0;r<4;++r)
#pragma unroll
    for (int q=0;q<5;++q){
      int c4 = (qb+q)*4;
      acc[r][q] = make_float4(bias[c4],bias[c4+1],bias[c4+2],bias[c4+3]);
    }

  float4 xv[4], xvn[4];
#pragma unroll
  for (int r=0;r<4;++r) xv[r] = xp[r*16];

#pragma unroll 1
  for (int d4=0; d4<16; ++d4){
    int dn = (d4+1) & 15;
#pragma unroll
    for (int r=0;r<4;++r) xvn[r] = xp[r*16 + dn];   // prefetch next depth-slice
#pragma unroll
    for (int dd=0; dd<4; ++dd){
#pragma unroll
      for (int q=0;q<5;++q){
        float4 wv = wl4[d4*4+dd][qb+q];
#pragma unroll
        for (int r=0;r<4;++r){
          float sc = (dd==0)?xv[r].x:((dd==1)?xv[r].y:((dd==2)?xv[r].z:xv[r].w));
          acc[r][q].x += sc*wv.x; acc[r][q].y += sc*wv.y;
          acc[r][q].z += sc*wv.z; acc[r][q].w += sc*wv.w;
        }
      }
    }
#pragma unroll
    for (int r=0;r<4;++r) xv[r] = xvn[r];
  }

#pragma unroll
  for (int r=0;r<4;++r){
    float4* ob = (float4*)(buf + (r0+r)*40 + qb*4);
#pragma unroll
    for (int q=0;q<5;++q) ob[q] = acc[r][q];
  }
}

// ---------------- Phase 2: scan, 16 lanes per batch element ----------------
// R8 structure (best measured). lane bits: j=bits0-2, p=bit3, elem=bits4-5.
// Paired float2 gate loads (new buf layout), padded-buffer unconditional
// prefetch. Masked DPPZ cumprod (guards 16-row edge AND lane-8 group edge).
__global__ __launch_bounds__(64,1) void qlstm_scan(
    const float* __restrict__ buf,
    const float* __restrict__ Wf, const float* __restrict__ Wi,
    const float* __restrict__ Wu, const float* __restrict__ Wo,
    const float* __restrict__ Wh2k,
    float* __restrict__ out,
    float* __restrict__ hstate, float* __restrict__ cstate,
    int t0, int tc, int initf, int lastf)
{
  int tid = threadIdx.x;          // 64
  int j = tid & 7;
  bool pb = (tid & 8) != 0;       // gate-pair select
  bool j4 = (j & 4) != 0;
  int b = blockIdx.x*4 + (tid >> 4);

  // slot A: p=0 -> f (sigmoid), p=1 -> u (tanh) ; slot B: i / o (sigmoid)
  const float* WA = pb ? Wu : Wf;
  const float* WB = pb ? Wo : Wi;
#define LDW(S_) \
  float wA##S_ = WA[(64+((j+S_)&7))*8 + j] * INV2PI; \
  float wB##S_ = WB[(64+((j+S_)&7))*8 + j] * INV2PI; \
  float wK##S_ = Wh2k[((j+S_)&7)*8 + j] * INV4PI;
  LDW(0) LDW(1) LDW(2) LDW(3) LDW(4) LDW(5) LDW(6) LDW(7)
#undef LDW

  float preY  = pb ? 1.0f : 0.5f;
  float postM = pb ? 1.0f : 0.5f;
  float postB = pb ? 0.0f : 0.5f;

  float h, c;
  if (initf){ h = 0.f; c = 0.f; }
  else { h = hstate[b*8+j]; c = cstate[b*8+j]; }

  const int S = BB*40;              // per-step stride (floats)
  int oAB = b*40 + (pb?16:0) + 2*j; // adjacent (A,B) float2
  int oK  = b*40 + 32 + j;

  float2 xABq[4]; float xKq[4];
#pragma unroll
  for (int i=0;i<4;++i){
    xABq[i] = *(const float2*)&buf[oAB + i*S];
    xKq[i]  = buf[oK + i*S];
  }
  int offAB = oAB + 4*S;            // unconditional cursors (buf padded +8 rows)
  int offK  = oK  + 4*S;
  int osto = (t0*BB + b)*8 + j;     // output cursor

  bool st = !pb;
  for (int tt4 = 0; tt4 < tc; tt4 += 4){
#pragma unroll
    for (int u=0; u<4; ++u){
      float xA = xABq[u].x, xB = xABq[u].y, xK = xKq[u];
      xABq[u] = *(const float2*)&buf[offAB];
      xKq[u]  = buf[offK];
      offAB += S; offK += S;

      // independent rotations of h (rotate-left-by-s within 16-row)
      float hr1 = DPPR(h,0x12F), hr2 = DPPR(h,0x12E), hr3 = DPPR(h,0x12D),
            hr4 = DPPR(h,0x12C), hr5 = DPPR(h,0x12B), hr6 = DPPR(h,0x12A),
            hr7 = DPPR(h,0x129);
      // matvecs, 2-accumulator trees
      float aA0 =       h*wA0;  aA0 = fmaf(hr2,wA2,aA0); aA0 = fmaf(hr4,wA4,aA0); aA0 = fmaf(hr6,wA6,aA0);
      float aA1 =     hr1*wA1;  aA1 = fmaf(hr3,wA3,aA1); aA1 = fmaf(hr5,wA5,aA1); aA1 = fmaf(hr7,wA7,aA1);
      float aA = aA0 + aA1;
      float aB0 =       h*wB0;  aB0 = fmaf(hr2,wB2,aB0); aB0 = fmaf(hr4,wB4,aB0); aB0 = fmaf(hr6,wB6,aB0);
      float aB1 =     hr1*wB1;  aB1 = fmaf(hr3,wB3,aB1); aB1 = fmaf(hr5,wB5,aB1); aB1 = fmaf(hr7,wB7,aB1);
      float aB = aB0 + aB1;
      float aK0 =       h*wK0;  aK0 = fmaf(hr2,wK2,aK0); aK0 = fmaf(hr4,wK4,aK0); aK0 = fmaf(hr6,wK6,aK0);
      float aK1 =     hr1*wK1;  aK1 = fmaf(hr3,wK3,aK1); aK1 = fmaf(hr5,wK5,aK1); aK1 = fmaf(hr7,wK7,aK1);
      float aK = aK0 + aK1;

      // kernel weight: |prod_j cos(2pi*(aK - xK))| over 8-lane j-group (DPP)
      float kv = fcosrev(aK - xK);
      kv *= DPPR(kv,0xB1);                       // xor1 (quad_perm)
      kv *= DPPR(kv,0x4E);                       // xor2 (quad_perm)
      { float t4a = DPPR(kv,0x124), t4b = DPPR(kv,0x12C);  // xor4 via ror4/ror12
        kv *= (j4 ? t4a : t4b); }
      float wk = fabsf(kv);

      // masked cumprod qlayer (masks guard 16-row edge AND lane-8 group edge)
#define CUMQ(ZV, GQ) { \
      float zz = (ZV); \
      float pz = zz, s_; \
      s_ = DPPZ(pz,0x111); pz *= ((j>=1)? s_ : 1.0f); \
      s_ = DPPZ(pz,0x112); pz *= ((j>=2)? s_ : 1.0f); \
      s_ = DPPZ(pz,0x114); pz *= ((j>=4)? s_ : 1.0f); \
      float q = (j==0)? 1.0f : zz; \
      q *= DPPR(q,0xB1); \
      q *= DPPR(q,0x4E); \
      { float q4a = DPPR(q,0x124), q4b = DPPR(q,0x12C); q *= (j4 ? q4a : q4b); } \
      GQ = ((j==0)? q : pz) * wk; }

      float gA, gB;
      CUMQ(fcosrev(aA + xA), gA)
      CUMQ(fcosrev(aB + xB), gB)
#undef CUMQ

      // slot A: tanh-core with per-lane pre/post constants; slot B: sigmoid
      float tA = tanh13(gA * preY);
      float actA = fmaf(tA, postM, postB);
      float tB = tanh13(gB * 0.5f);
      float actB = fmaf(tB, 0.5f, 0.5f);

      // cross-pair gather via ror:8 (lane l <-> l^8)
      float gAo = DPPR(actA,0x128);
      float gBo = DPPR(actB,0x128);
      float fv = pb ? gAo  : actA;
      float uv = pb ? actA : gAo;
      float iv = pb ? gBo  : actB;
      float ov = pb ? actB : gBo;

      c = fmaf(fv, c, iv*uv);
      // tanh(c) via Pade(5,4): |c| <= ~2.1, err <= 3e-5 (one rcp on the chain)
      float c2 = c * c;
      float num = fmaf(c2, c2 + 105.0f, 945.0f);
      float den = fmaf(c2, fmaf(c2, 15.0f, 420.0f), 945.0f);
      float tch = c * num * frcp(den);
      h = ov * tch;

      if (st) out[osto] = h;
      osto += BB*8;
    }
  }

  if (st){
    if (lastf){
      out[(size_t)TT*BB*8 + (size_t)b*8 + j] = h;
      out[(size_t)TT*BB*8 + (size_t)BB*8 + (size_t)b*8 + j] = c;
    } else {
      hstate[b*8+j] = h;
      cstate[b*8+j] = c;
    }
  }
}

extern "C" void kernel_launch(void* const* d_in, const int* in_sizes, int n_in,
                              void* d_out, int out_size, void* d_ws, size_t ws_size,
                              hipStream_t stream)
{
  const float* x    = (const float*)d_in[0];
  const float* Wf   = (const float*)d_in[1];
  const float* bf   = (const float*)d_in[2];
  const float* thf  = (const float*)d_in[3];
  const float* Wi   = (const float*)d_in[4];
  const float* bi   = (const float*)d_in[5];
  const float* thi  = (const float*)d_in[6];
  const float* Wu   = (const float*)d_in[7];
  const float* bu   = (const float*)d_in[8];
  const float* thu  = (const float*)d_in[9];
  const float* Wo   = (const float*)d_in[10];
  const float* bo   = (const float*)d_in[11];
  const float* tho  = (const float*)d_in[12];
  const float* Wh2k = (const float*)d_in[13];
  const float* bh2k = (const float*)d_in[14];
  const float* Wi2k = (const float*)d_in[15];
  const float* bi2k = (const float*)d_in[16];
  float* out = (float*)d_out;

  // ws layout: hstate[8192 f] | cstate[8192 f] | xpre buf [tc+8][BB][40]
  float* hstate = (float*)d_ws;
  float* cstate = hstate + BB*8;
  float* buf    = cstate + BB*8;
  long long avail = (long long)ws_size - (long long)(2*BB*8*sizeof(float));
  const long long per_step = 40ll*BB*sizeof(float);  // 160 KiB per time step
  int tc = TT;
  while (tc > 4 && (long long)(tc+8)*per_step > avail) tc >>= 1;

  for (int t0 = 0; t0 < TT; t0 += tc){
    int cur = (TT - t0 < tc) ? (TT - t0) : tc;
    qlstm_proj<<<(cur*BB)/512, 256, 0, stream>>>(
        x + (size_t)t0*BB*64,
        Wf,bf,thf, Wi,bi,thi, Wu,bu,thu, Wo,bo,tho,
        bh2k, Wi2k, bi2k, buf);
    qlstm_scan<<<BB/4, 64, 0, stream>>>(
        buf, Wf, Wi, Wu, Wo, Wh2k, out, hstate, cstate,
        t0, cur, (t0==0)?1:0, (t0+cur>=TT)?1:0);
  }
}

// Round 11
// 219.409 us; speedup vs baseline: 1.8843x; 1.4010x over previous
//
#include <hip/hip_runtime.h>

#define TT 512
#define BB 1024
#define INV2PI 0.15915494309189535f
#define INV4PI 0.07957747154594767f

typedef __attribute__((ext_vector_type(8))) short short8;
typedef __attribute__((ext_vector_type(4))) float floatx4;

__device__ __forceinline__ float frcp(float x){ return __builtin_amdgcn_rcpf(x); }
__device__ __forceinline__ float fcosrev(float r){
  float rr = r - floorf(r);
  return __builtin_amdgcn_cosf(rr);
}
__device__ __forceinline__ float tanh13(float y){
  float s = y*y;
  float p = fmaf(s, 0.00359213f, -0.00886324f);
  p = fmaf(p, s, 0.02186948f);
  p = fmaf(p, s, -0.05396825f);
  p = fmaf(p, s, 0.13333333f);
  p = fmaf(p, s, -0.33333333f);
  p = fmaf(p, s, 1.0f);
  return y*p;
}

#define DPPZ(v, ctrl) __int_as_float(__builtin_amdgcn_update_dpp(0, __float_as_int(v), (ctrl), 0xF, 0xF, true))
#define DPPR(v, ctrl) __int_as_float(__builtin_amdgcn_update_dpp(__float_as_int(v), __float_as_int(v), (ctrl), 0xF, 0xF, false))

// bf16 round-to-nearest-even (bits)
__device__ __forceinline__ unsigned bf16rne(float f){
  unsigned u = __float_as_uint(f);
  return (u + 0x7FFFu + ((u >> 16) & 1u)) >> 16;
}
union U8 { unsigned u[4]; short8 s; };
// split 8 fp32 into bf16 hi + bf16 lo fragments (packed)
__device__ __forceinline__ void splitpack(const float* v, short8& hi, short8& lo){
  U8 H, L;
#pragma unroll
  for (int p=0;p<4;++p){
    float a = v[2*p], b = v[2*p+1];
    unsigned ha = bf16rne(a), hb = bf16rne(b);
    float ra = a - __uint_as_float(ha << 16);
    float rb = b - __uint_as_float(hb << 16);
    H.u[p] = ha | (hb << 16);
    L.u[p] = bf16rne(ra) | (bf16rne(rb) << 16);
  }
  hi = H.s; lo = L.s;
}

// Column layout of buf rows (40 floats) — unchanged from R10:
//  c in [0,32): pairIdx=c>>1 (j=pairIdx&7, pb=pairIdx>>3), slot=c&1, g=2*pb+slot
//               value = (x@Wg[:64] + bg + thg) * INV2PI
//  c in [32,40): j=c-32, value = (x@Wi2k + bi2k - bh2k) * INV4PI

// ---------------- Phase 1: MFMA projection ----------------
// [rows x 64] @ [64 x 40] via mfma_f32_16x16x32_bf16, hi/lo bf16 split.
// Per 16-row tile: 3 col-tiles x (2 K-halves x 3 products) = 18 mfma.
// Weights live in per-lane registers (no LDS). Bias in fp32 acc init.
__global__ __launch_bounds__(256,1) void qlstm_proj(
    const float* __restrict__ x,
    const float* __restrict__ Wf, const float* __restrict__ bf, const float* __restrict__ thf,
    const float* __restrict__ Wi, const float* __restrict__ bi, const float* __restrict__ thi,
    const float* __restrict__ Wu, const float* __restrict__ bu, const float* __restrict__ thu,
    const float* __restrict__ Wo, const float* __restrict__ bo, const float* __restrict__ tho,
    const float* __restrict__ bh2k,
    const float* __restrict__ Wi2k, const float* __restrict__ bi2k,
    float* __restrict__ buf, int ntiles)
{
  int lane = threadIdx.x & 63;
  int n  = lane & 15;          // col within tile / A row within tile
  int kb = lane >> 4;          // k-block (8 consecutive k per block)

  // per-lane weight pointer/scale/bias for each col-tile
  short8 Bh[3][2], Bl[3][2];
  float biasv[3];
#pragma unroll
  for (int ct=0; ct<3; ++ct){
    int c = ct*16 + n;
    const float* wp; float wsc; float bv;
    if (c < 32){
      int pi = c>>1, slot = c&1, j = pi&7, pbc = pi>>3, g = 2*pbc + slot;
      const float* W  = (g==0)?Wf:((g==1)?Wi:((g==2)?Wu:Wo));
      const float* bp = (g==0)?bf:((g==1)?bi:((g==2)?bu:bo));
      const float* tp = (g==0)?thf:((g==1)?thi:((g==2)?thu:tho));
      wp = W + j; wsc = INV2PI; bv = (bp[j] + tp[j]) * INV2PI;
    } else if (c < 40){
      wp = Wi2k + (c-32); wsc = INV4PI; bv = (bi2k[c-32] - bh2k[c-32]) * INV4PI;
    } else {
      wp = Wf; wsc = 0.f; bv = 0.f;
    }
    biasv[ct] = bv;
#pragma unroll
    for (int kh=0; kh<2; ++kh){
      float wv[8];
#pragma unroll
      for (int e=0;e<8;++e) wv[e] = wp[(kh*32 + kb*8 + e)*8] * wsc;
      splitpack(wv, Bh[ct][kh], Bl[ct][kh]);
    }
  }

  int wid = blockIdx.x*4 + (threadIdx.x >> 6);
  int nw  = gridDim.x*4;
  const float4* x4 = (const float4*)x;

  for (int t = wid; t < ntiles; t += nw){
    int R = t*16;
    floatx4 a0, a1, a2;
#pragma unroll
    for (int r=0;r<4;++r){ a0[r]=biasv[0]; a1[r]=biasv[1]; a2[r]=biasv[2]; }

#pragma unroll
    for (int kh=0; kh<2; ++kh){
      int fi = (R + n)*16 + kh*8 + kb*2;
      float4 v0 = x4[fi], v1 = x4[fi+1];
      float av[8] = {v0.x,v0.y,v0.z,v0.w, v1.x,v1.y,v1.z,v1.w};
      short8 Ah, Al; splitpack(av, Ah, Al);
      a0 = __builtin_amdgcn_mfma_f32_16x16x32_bf16(Ah, Bh[0][kh], a0, 0,0,0);
      a1 = __builtin_amdgcn_mfma_f32_16x16x32_bf16(Ah, Bh[1][kh], a1, 0,0,0);
      a2 = __builtin_amdgcn_mfma_f32_16x16x32_bf16(Ah, Bh[2][kh], a2, 0,0,0);
      a0 = __builtin_amdgcn_mfma_f32_16x16x32_bf16(Al, Bh[0][kh], a0, 0,0,0);
      a1 = __builtin_amdgcn_mfma_f32_16x16x32_bf16(Al, Bh[1][kh], a1, 0,0,0);
      a2 = __builtin_amdgcn_mfma_f32_16x16x32_bf16(Al, Bh[2][kh], a2, 0,0,0);
      a0 = __builtin_amdgcn_mfma_f32_16x16x32_bf16(Ah, Bl[0][kh], a0, 0,0,0);
      a1 = __builtin_amdgcn_mfma_f32_16x16x32_bf16(Ah, Bl[1][kh], a1, 0,0,0);
      a2 = __builtin_amdgcn_mfma_f32_16x16x32_bf16(Ah, Bl[2][kh], a2, 0,0,0);
    }

    // C layout (verified): col = lane&15, row = (lane>>4)*4 + reg
#pragma unroll
    for (int r=0;r<4;++r){
      int row = R + kb*4 + r;
      float* rp = buf + (size_t)row*40;
      rp[n]      = a0[r];
      rp[16 + n] = a1[r];
      if (n < 8) rp[32 + n] = a2[r];
    }
  }
}

// ---------------- Phase 2: scan (R10 verbatim — best measured) -------------
__global__ __launch_bounds__(64,1) void qlstm_scan(
    const float* __restrict__ buf,
    const float* __restrict__ Wf, const float* __restrict__ Wi,
    const float* __restrict__ Wu, const float* __restrict__ Wo,
    const float* __restrict__ Wh2k,
    float* __restrict__ out,
    float* __restrict__ hstate, float* __restrict__ cstate,
    int t0, int tc, int initf, int lastf)
{
  int tid = threadIdx.x;          // 64
  int j = tid & 7;
  bool pb = (tid & 8) != 0;
  bool j4 = (j & 4) != 0;
  int b = blockIdx.x*4 + (tid >> 4);

  const float* WA = pb ? Wu : Wf;
  const float* WB = pb ? Wo : Wi;
#define LDW(S_) \
  float wA##S_ = WA[(64+((j+S_)&7))*8 + j] * INV2PI; \
  float wB##S_ = WB[(64+((j+S_)&7))*8 + j] * INV2PI; \
  float wK##S_ = Wh2k[((j+S_)&7)*8 + j] * INV4PI;
  LDW(0) LDW(1) LDW(2) LDW(3) LDW(4) LDW(5) LDW(6) LDW(7)
#undef LDW

  float preY  = pb ? 1.0f : 0.5f;
  float postM = pb ? 1.0f : 0.5f;
  float postB = pb ? 0.0f : 0.5f;

  float h, c;
  if (initf){ h = 0.f; c = 0.f; }
  else { h = hstate[b*8+j]; c = cstate[b*8+j]; }

  const int S = BB*40;
  int oAB = b*40 + (pb?16:0) + 2*j;
  int oK  = b*40 + 32 + j;

  float2 xABq[4]; float xKq[4];
#pragma unroll
  for (int i=0;i<4;++i){
    xABq[i] = *(const float2*)&buf[oAB + i*S];
    xKq[i]  = buf[oK + i*S];
  }
  int offAB = oAB + 4*S;
  int offK  = oK  + 4*S;
  int osto = (t0*BB + b)*8 + j;

  bool st = !pb;
  for (int tt4 = 0; tt4 < tc; tt4 += 4){
#pragma unroll
    for (int u=0; u<4; ++u){
      float xA = xABq[u].x, xB = xABq[u].y, xK = xKq[u];
      xABq[u] = *(const float2*)&buf[offAB];
      xKq[u]  = buf[offK];
      offAB += S; offK += S;

      float hr1 = DPPR(h,0x12F), hr2 = DPPR(h,0x12E), hr3 = DPPR(h,0x12D),
            hr4 = DPPR(h,0x12C), hr5 = DPPR(h,0x12B), hr6 = DPPR(h,0x12A),
            hr7 = DPPR(h,0x129);
      float aA0 =       h*wA0;  aA0 = fmaf(hr2,wA2,aA0); aA0 = fmaf(hr4,wA4,aA0); aA0 = fmaf(hr6,wA6,aA0);
      float aA1 =     hr1*wA1;  aA1 = fmaf(hr3,wA3,aA1); aA1 = fmaf(hr5,wA5,aA1); aA1 = fmaf(hr7,wA7,aA1);
      float aA = aA0 + aA1;
      float aB0 =       h*wB0;  aB0 = fmaf(hr2,wB2,aB0); aB0 = fmaf(hr4,wB4,aB0); aB0 = fmaf(hr6,wB6,aB0);
      float aB1 =     hr1*wB1;  aB1 = fmaf(hr3,wB3,aB1); aB1 = fmaf(hr5,wB5,aB1); aB1 = fmaf(hr7,wB7,aB1);
      float aB = aB0 + aB1;
      float aK0 =       h*wK0;  aK0 = fmaf(hr2,wK2,aK0); aK0 = fmaf(hr4,wK4,aK0); aK0 = fmaf(hr6,wK6,aK0);
      float aK1 =     hr1*wK1;  aK1 = fmaf(hr3,wK3,aK1); aK1 = fmaf(hr5,wK5,aK1); aK1 = fmaf(hr7,wK7,aK1);
      float aK = aK0 + aK1;

      float kv = fcosrev(aK - xK);
      kv *= DPPR(kv,0xB1);
      kv *= DPPR(kv,0x4E);
      { float t4a = DPPR(kv,0x124), t4b = DPPR(kv,0x12C);
        kv *= (j4 ? t4a : t4b); }
      float wk = fabsf(kv);

#define CUMQ(ZV, GQ) { \
      float zz = (ZV); \
      float pz = zz, s_; \
      s_ = DPPZ(pz,0x111); pz *= ((j>=1)? s_ : 1.0f); \
      s_ = DPPZ(pz,0x112); pz *= ((j>=2)? s_ : 1.0f); \
      s_ = DPPZ(pz,0x114); pz *= ((j>=4)? s_ : 1.0f); \
      float q = (j==0)? 1.0f : zz; \
      q *= DPPR(q,0xB1); \
      q *= DPPR(q,0x4E); \
      { float q4a = DPPR(q,0x124), q4b = DPPR(q,0x12C); q *= (j4 ? q4a : q4b); } \
      GQ = ((j==0)? q : pz) * wk; }

      float gA, gB;
      CUMQ(fcosrev(aA + xA), gA)
      CUMQ(fcosrev(aB + xB), gB)
#undef CUMQ

      float tA = tanh13(gA * preY);
      float actA = fmaf(tA, postM, postB);
      float tB = tanh13(gB * 0.5f);
      float actB = fmaf(tB, 0.5f, 0.5f);

      float gAo = DPPR(actA,0x128);
      float gBo = DPPR(actB,0x128);
      float fv = pb ? gAo  : actA;
      float uv = pb ? actA : gAo;
      float iv = pb ? gBo  : actB;
      float ov = pb ? actB : gBo;

      c = fmaf(fv, c, iv*uv);
      float c2 = c * c;
      float num = fmaf(c2, c2 + 105.0f, 945.0f);
      float den = fmaf(c2, fmaf(c2, 15.0f, 420.0f), 945.0f);
      float tch = c * num * frcp(den);
      h = ov * tch;

      if (st) out[osto] = h;
      osto += BB*8;
    }
  }

  if (st){
    if (lastf){
      out[(size_t)TT*BB*8 + (size_t)b*8 + j] = h;
      out[(size_t)TT*BB*8 + (size_t)BB*8 + (size_t)b*8 + j] = c;
    } else {
      hstate[b*8+j] = h;
      cstate[b*8+j] = c;
    }
  }
}

extern "C" void kernel_launch(void* const* d_in, const int* in_sizes, int n_in,
                              void* d_out, int out_size, void* d_ws, size_t ws_size,
                              hipStream_t stream)
{
  const float* x    = (const float*)d_in[0];
  const float* Wf   = (const float*)d_in[1];
  const float* bf   = (const float*)d_in[2];
  const float* thf  = (const float*)d_in[3];
  const float* Wi   = (const float*)d_in[4];
  const float* bi   = (const float*)d_in[5];
  const float* thi  = (const float*)d_in[6];
  const float* Wu   = (const float*)d_in[7];
  const float* bu   = (const float*)d_in[8];
  const float* thu  = (const float*)d_in[9];
  const float* Wo   = (const float*)d_in[10];
  const float* bo   = (const float*)d_in[11];
  const float* tho  = (const float*)d_in[12];
  const float* Wh2k = (const float*)d_in[13];
  const float* bh2k = (const float*)d_in[14];
  const float* Wi2k = (const float*)d_in[15];
  const float* bi2k = (const float*)d_in[16];
  float* out = (float*)d_out;

  // ws layout: hstate[8192 f] | cstate[8192 f] | xpre buf [tc+8][BB][40]
  float* hstate = (float*)d_ws;
  float* cstate = hstate + BB*8;
  float* buf    = cstate + BB*8;
  long long avail = (long long)ws_size - (long long)(2*BB*8*sizeof(float));
  const long long per_step = 40ll*BB*sizeof(float);  // 160 KiB per time step
  int tc = TT;
  while (tc > 4 && (long long)(tc+8)*per_step > avail) tc >>= 1;

  for (int t0 = 0; t0 < TT; t0 += tc){
    int cur = (TT - t0 < tc) ? (TT - t0) : tc;
    int ntiles = cur*BB/16;
    int grid = (ntiles + 3) / 4; if (grid > 1024) grid = 1024;
    qlstm_proj<<<grid, 256, 0, stream>>>(
        x + (size_t)t0*BB*64,
        Wf,bf,thf, Wi,bi,thi, Wu,bu,thu, Wo,bo,tho,
        bh2k, Wi2k, bi2k, buf, ntiles);
    qlstm_scan<<<BB/4, 64, 0, stream>>>(
        buf, Wf, Wi, Wu, Wo, Wh2k, out, hstate, cstate,
        t0, cur, (t0==0)?1:0, (t0+cur>=TT)?1:0);
  }
}

// Round 12
// 211.915 us; speedup vs baseline: 1.9509x; 1.0354x over previous
//
#include <hip/hip_runtime.h>

#define TT 512
#define BB 1024
#define INV2PI 0.15915494309189535f
#define INV4PI 0.07957747154594767f

__device__ __forceinline__ float frcp(float x){ return __builtin_amdgcn_rcpf(x); }
__device__ __forceinline__ float fcosrev(float r){
  float rr = r - floorf(r);
  return __builtin_amdgcn_cosf(rr);
}
__device__ __forceinline__ float tanh13(float y){
  float s = y*y;
  float p = fmaf(s, 0.00359213f, -0.00886324f);
  p = fmaf(p, s, 0.02186948f);
  p = fmaf(p, s, -0.05396825f);
  p = fmaf(p, s, 0.13333333f);
  p = fmaf(p, s, -0.33333333f);
  p = fmaf(p, s, 1.0f);
  return y*p;
}

#define DPPZ(v, ctrl) __int_as_float(__builtin_amdgcn_update_dpp(0, __float_as_int(v), (ctrl), 0xF, 0xF, true))
#define DPPR(v, ctrl) __int_as_float(__builtin_amdgcn_update_dpp(__float_as_int(v), __float_as_int(v), (ctrl), 0xF, 0xF, false))

// Column layout of a 40-float xpre row (same as R10):
//  c in [0,32): pairIdx=c>>1 (j=pairIdx&7, pb=pairIdx>>3), slot=c&1, g=2*pb+slot
//               value = (x@Wg[:64] + bg + thg) * INV2PI
//  c in [32,40): j=c-32, value = (x@Wi2k + bi2k - bh2k) * INV4PI

// Fused: wave 0 scans 4 elements (R10 math verbatim, xpre from LDS);
// waves 1-2 project 32-step chunks into triple-buffered LDS, 2 chunks ahead;
// wave 3 only participates in barriers. One launch for all 512 steps.
__global__ __launch_bounds__(256,1) void qlstm_fused(
    const float* __restrict__ x,
    const float* __restrict__ Wf, const float* __restrict__ bfp, const float* __restrict__ thf,
    const float* __restrict__ Wi, const float* __restrict__ bip, const float* __restrict__ thi,
    const float* __restrict__ Wu, const float* __restrict__ bup, const float* __restrict__ thu,
    const float* __restrict__ Wo, const float* __restrict__ bop, const float* __restrict__ tho,
    const float* __restrict__ Wh2k, const float* __restrict__ bh2k,
    const float* __restrict__ Wi2k, const float* __restrict__ bi2k,
    float* __restrict__ out)
{
  __shared__ float wl[64][40];
  __shared__ float bias[40];
  __shared__ float xp[3][32][4][40];   // [buf][t_local][b_local][col]

  int tid = threadIdx.x;
  int b0 = blockIdx.x * 4;

  // ---- fill weight/bias LDS (all threads) ----
  for (int idx = tid; idx < 64*40; idx += 256){
    int d = idx / 40, cc = idx - d*40;
    float v;
    if (cc < 32){
      int pi = cc >> 1, slot = cc & 1;
      int jj = pi & 7, pbc = pi >> 3;
      int g = 2*pbc + slot;
      const float* W = (g==0)?Wf:((g==1)?Wi:((g==2)?Wu:Wo));
      v = W[d*8+jj] * INV2PI;
    } else {
      v = Wi2k[d*8 + (cc-32)] * INV4PI;
    }
    wl[d][cc] = v;
  }
  if (tid < 40){
    int cc = tid; float v;
    if (cc < 32){
      int pi = cc >> 1, slot = cc & 1;
      int jj = pi & 7, pbc = pi >> 3;
      int g = 2*pbc + slot;
      const float* bp = (g==0)?bfp:((g==1)?bip:((g==2)?bup:bop));
      const float* tp = (g==0)?thf:((g==1)?thi:((g==2)?thu:tho));
      v = (bp[jj] + tp[jj]) * INV2PI;
    } else {
      v = (bi2k[cc-32] - bh2k[cc-32]) * INV4PI;
    }
    bias[cc] = v;
  }

  int wid = tid >> 6;
  int j  = tid & 7;
  bool pb = (tid & 8) != 0;
  bool j4 = (j & 4) != 0;
  int bl = (tid >> 4) & 3;

  // producer lane mapping (waves 1-2)
  int plane = tid - 64;                // 0..127
  int ptl = plane >> 2, pbl = plane & 3;

  auto produce = [&](int ck){
    int t = ck*32 + ptl;
    const float4* xr = (const float4*)(x + ((size_t)t*BB + b0 + pbl)*64);
    float4 acc[10];
    const float4* b4 = (const float4*)bias;
#pragma unroll
    for (int q=0;q<10;++q) acc[q] = b4[q];
#pragma unroll 1
    for (int k4=0;k4<16;++k4){
      float4 xv = xr[k4];
#pragma unroll
      for (int dd=0; dd<4; ++dd){
        float s = (dd==0)?xv.x:((dd==1)?xv.y:((dd==2)?xv.z:xv.w));
        const float4* w4 = (const float4*)&wl[k4*4+dd][0];
#pragma unroll
        for (int q=0;q<10;++q){
          acc[q].x += s*w4[q].x; acc[q].y += s*w4[q].y;
          acc[q].z += s*w4[q].z; acc[q].w += s*w4[q].w;
        }
      }
    }
    float4* dst = (float4*)&xp[ck%3][ptl][pbl][0];
#pragma unroll
    for (int q=0;q<10;++q) dst[q] = acc[q];
  };

  // scan-wave weights (global loads, independent of LDS fill)
  const float* WA = pb ? Wu : Wf;
  const float* WB = pb ? Wo : Wi;
  float wA0,wA1,wA2,wA3,wA4,wA5,wA6,wA7;
  float wB0,wB1,wB2,wB3,wB4,wB5,wB6,wB7;
  float wK0,wK1,wK2,wK3,wK4,wK5,wK6,wK7;
#define LDW(S_) \
  wA##S_ = WA[(64+((j+S_)&7))*8 + j] * INV2PI; \
  wB##S_ = WB[(64+((j+S_)&7))*8 + j] * INV2PI; \
  wK##S_ = Wh2k[((j+S_)&7)*8 + j] * INV4PI;
  LDW(0) LDW(1) LDW(2) LDW(3) LDW(4) LDW(5) LDW(6) LDW(7)
#undef LDW

  float preY  = pb ? 1.0f : 0.5f;
  float postM = pb ? 1.0f : 0.5f;
  float postB = pb ? 0.0f : 0.5f;

  float h = 0.f, c = 0.f;

  __syncthreads();                     // B0: wl/bias ready

  if (wid == 1 || wid == 2){
    produce(0);
    produce(1);
  }

  __syncthreads();                     // B1: chunks 0,1 ready

  int oAB = bl*40 + (pb?16:0) + 2*j;
  int oK  = bl*40 + 32 + j;
  float2 xABq[4]; float xKq[4];
  int osto = (b0 + bl)*8 + j;
  bool st = !pb;

  if (wid == 0){
#pragma unroll
    for (int i=0;i<4;++i){
      const float* sp = &xp[0][i][0][0];
      xABq[i] = *(const float2*)&sp[oAB];
      xKq[i]  = sp[oK];
    }
  }

  for (int k = 0; k < 16; ++k){
    if (wid == 0){
      const float* baseA = &xp[k%3][0][0][0];
      const float* baseB = (k < 15) ? &xp[(k+1)%3][0][0][0] : &xp[k%3][0][0][0];
#pragma unroll 1
      for (int s4 = 0; s4 < 32; s4 += 4){
#pragma unroll
        for (int u = 0; u < 4; ++u){
          int s = s4 + u;
          float xA = xABq[u].x, xB = xABq[u].y, xK = xKq[u];
          int ps = s + 4;
          const float* pp = (ps < 32) ? (baseA + ps*160)
                                      : ((k < 15) ? (baseB + (ps-32)*160)
                                                  : (baseA + 31*160));
          xABq[u] = *(const float2*)&pp[oAB];
          xKq[u]  = pp[oK];

          float hr1 = DPPR(h,0x12F), hr2 = DPPR(h,0x12E), hr3 = DPPR(h,0x12D),
                hr4 = DPPR(h,0x12C), hr5 = DPPR(h,0x12B), hr6 = DPPR(h,0x12A),
                hr7 = DPPR(h,0x129);
          float aA0 =       h*wA0;  aA0 = fmaf(hr2,wA2,aA0); aA0 = fmaf(hr4,wA4,aA0); aA0 = fmaf(hr6,wA6,aA0);
          float aA1 =     hr1*wA1;  aA1 = fmaf(hr3,wA3,aA1); aA1 = fmaf(hr5,wA5,aA1); aA1 = fmaf(hr7,wA7,aA1);
          float aA = aA0 + aA1;
          float aB0 =       h*wB0;  aB0 = fmaf(hr2,wB2,aB0); aB0 = fmaf(hr4,wB4,aB0); aB0 = fmaf(hr6,wB6,aB0);
          float aB1 =     hr1*wB1;  aB1 = fmaf(hr3,wB3,aB1); aB1 = fmaf(hr5,wB5,aB1); aB1 = fmaf(hr7,wB7,aB1);
          float aB = aB0 + aB1;
          float aK0 =       h*wK0;  aK0 = fmaf(hr2,wK2,aK0); aK0 = fmaf(hr4,wK4,aK0); aK0 = fmaf(hr6,wK6,aK0);
          float aK1 =     hr1*wK1;  aK1 = fmaf(hr3,wK3,aK1); aK1 = fmaf(hr5,wK5,aK1); aK1 = fmaf(hr7,wK7,aK1);
          float aK = aK0 + aK1;

          float kv = fcosrev(aK - xK);
          kv *= DPPR(kv,0xB1);
          kv *= DPPR(kv,0x4E);
          { float t4a = DPPR(kv,0x124), t4b = DPPR(kv,0x12C);
            kv *= (j4 ? t4a : t4b); }
          float wk = fabsf(kv);

#define CUMQ(ZV, GQ) { \
          float zz = (ZV); \
          float pz = zz, s_; \
          s_ = DPPZ(pz,0x111); pz *= ((j>=1)? s_ : 1.0f); \
          s_ = DPPZ(pz,0x112); pz *= ((j>=2)? s_ : 1.0f); \
          s_ = DPPZ(pz,0x114); pz *= ((j>=4)? s_ : 1.0f); \
          float q = (j==0)? 1.0f : zz; \
          q *= DPPR(q,0xB1); \
          q *= DPPR(q,0x4E); \
          { float q4a = DPPR(q,0x124), q4b = DPPR(q,0x12C); q *= (j4 ? q4a : q4b); } \
          GQ = ((j==0)? q : pz) * wk; }

          float gA, gB;
          CUMQ(fcosrev(aA + xA), gA)
          CUMQ(fcosrev(aB + xB), gB)
#undef CUMQ

          float tA = tanh13(gA * preY);
          float actA = fmaf(tA, postM, postB);
          float tB = tanh13(gB * 0.5f);
          float actB = fmaf(tB, 0.5f, 0.5f);

          float gAo = DPPR(actA,0x128);
          float gBo = DPPR(actB,0x128);
          float fv = pb ? gAo  : actA;
          float uv = pb ? actA : gAo;
          float iv = pb ? gBo  : actB;
          float ov = pb ? actB : gBo;

          c = fmaf(fv, c, iv*uv);
          float c2 = c * c;
          float num = fmaf(c2, c2 + 105.0f, 945.0f);
          float den = fmaf(c2, fmaf(c2, 15.0f, 420.0f), 945.0f);
          float tch = c * num * frcp(den);
          h = ov * tch;

          if (st) out[osto] = h;
          osto += BB*8;
        }
      }
    } else if (wid == 1 || wid == 2){
      if (k + 2 < 16) produce(k + 2);
    }
    __syncthreads();
  }

  if (wid == 0 && st){
    out[(size_t)TT*BB*8 + (size_t)(b0+bl)*8 + j] = h;
    out[(size_t)TT*BB*8 + (size_t)BB*8 + (size_t)(b0+bl)*8 + j] = c;
  }
}

extern "C" void kernel_launch(void* const* d_in, const int* in_sizes, int n_in,
                              void* d_out, int out_size, void* d_ws, size_t ws_size,
                              hipStream_t stream)
{
  const float* x    = (const float*)d_in[0];
  const float* Wf   = (const float*)d_in[1];
  const float* bf   = (const float*)d_in[2];
  const float* thf  = (const float*)d_in[3];
  const float* Wi   = (const float*)d_in[4];
  const float* bi   = (const float*)d_in[5];
  const float* thi  = (const float*)d_in[6];
  const float* Wu   = (const float*)d_in[7];
  const float* bu   = (const float*)d_in[8];
  const float* thu  = (const float*)d_in[9];
  const float* Wo   = (const float*)d_in[10];
  const float* bo   = (const float*)d_in[11];
  const float* tho  = (const float*)d_in[12];
  const float* Wh2k = (const float*)d_in[13];
  const float* bh2k = (const float*)d_in[14];
  const float* Wi2k = (const float*)d_in[15];
  const float* bi2k = (const float*)d_in[16];
  float* out = (float*)d_out;
  (void)d_ws; (void)ws_size; (void)in_sizes; (void)n_in; (void)out_size;

  qlstm_fused<<<BB/4, 256, 0, stream>>>(
      x, Wf,bf,thf, Wi,bi,thi, Wu,bu,thu, Wo,bo,tho,
      Wh2k, bh2k, Wi2k, bi2k, out);
}

// Round 13
// 182.222 us; speedup vs baseline: 2.2688x; 1.1630x over previous
//
#include <hip/hip_runtime.h>

#define TT 512
#define BB 1024
#define INV2PI 0.15915494309189535f
#define INV4PI 0.07957747154594767f

typedef __attribute__((ext_vector_type(2))) float f2;

__device__ __forceinline__ float frcp(float x){ return __builtin_amdgcn_rcpf(x); }
__device__ __forceinline__ float fcosrev(float r){
  float rr = r - floorf(r);
  return __builtin_amdgcn_cosf(rr);
}

#define DPPZ(v, ctrl) __int_as_float(__builtin_amdgcn_update_dpp(0, __float_as_int(v), (ctrl), 0xF, 0xF, true))
#define DPPR(v, ctrl) __int_as_float(__builtin_amdgcn_update_dpp(__float_as_int(v), __float_as_int(v), (ctrl), 0xF, 0xF, false))

// Column layout of a 40-float xpre row (same as R10/R12):
//  c in [0,32): pairIdx=c>>1 (j=pairIdx&7, pb=pairIdx>>3), slot=c&1, g=2*pb+slot
//               value = (x@Wg[:64] + bg + thg) * INV2PI
//  c in [32,40): j=c-32, value = (x@Wi2k + bi2k - bh2k) * INV4PI

// Fused: wave 0 scans 4 elements; waves 1-2 project 32-step chunks into
// triple-buffered LDS, 2 chunks ahead; wave 3 barrier-only.
__global__ __launch_bounds__(256,1) void qlstm_fused(
    const float* __restrict__ x,
    const float* __restrict__ Wf, const float* __restrict__ bfp, const float* __restrict__ thf,
    const float* __restrict__ Wi, const float* __restrict__ bip, const float* __restrict__ thi,
    const float* __restrict__ Wu, const float* __restrict__ bup, const float* __restrict__ thu,
    const float* __restrict__ Wo, const float* __restrict__ bop, const float* __restrict__ tho,
    const float* __restrict__ Wh2k, const float* __restrict__ bh2k,
    const float* __restrict__ Wi2k, const float* __restrict__ bi2k,
    float* __restrict__ out)
{
  __shared__ float wl[64][40];
  __shared__ float bias[40];
  __shared__ float xp[3][32][4][40];   // [buf][t_local][b_local][col]

  int tid = threadIdx.x;
  int b0 = blockIdx.x * 4;

  // ---- fill weight/bias LDS (all threads) ----
  for (int idx = tid; idx < 64*40; idx += 256){
    int d = idx / 40, cc = idx - d*40;
    float v;
    if (cc < 32){
      int pi = cc >> 1, slot = cc & 1;
      int jj = pi & 7, pbc = pi >> 3;
      int g = 2*pbc + slot;
      const float* W = (g==0)?Wf:((g==1)?Wi:((g==2)?Wu:Wo));
      v = W[d*8+jj] * INV2PI;
    } else {
      v = Wi2k[d*8 + (cc-32)] * INV4PI;
    }
    wl[d][cc] = v;
  }
  if (tid < 40){
    int cc = tid; float v;
    if (cc < 32){
      int pi = cc >> 1, slot = cc & 1;
      int jj = pi & 7, pbc = pi >> 3;
      int g = 2*pbc + slot;
      const float* bp = (g==0)?bfp:((g==1)?bip:((g==2)?bup:bop));
      const float* tp = (g==0)?thf:((g==1)?thi:((g==2)?thu:tho));
      v = (bp[jj] + tp[jj]) * INV2PI;
    } else {
      v = (bi2k[cc-32] - bh2k[cc-32]) * INV4PI;
    }
    bias[cc] = v;
  }

  int wid = tid >> 6;
  int j  = tid & 7;
  bool pb = (tid & 8) != 0;
  bool j4 = (j & 4) != 0;
  int bl = (tid >> 4) & 3;

  // producer lane mapping (waves 1-2)
  int plane = tid - 64;                // 0..127
  int ptl = plane >> 2, pbl = plane & 3;

  auto produce = [&](int ck){
    int t = ck*32 + ptl;
    const float4* xr = (const float4*)(x + ((size_t)t*BB + b0 + pbl)*64);
    float4 acc[10];
    const float4* b4 = (const float4*)bias;
#pragma unroll
    for (int q=0;q<10;++q) acc[q] = b4[q];
#pragma unroll 1
    for (int k4=0;k4<16;++k4){
      float4 xv = xr[k4];
#pragma unroll
      for (int dd=0; dd<4; ++dd){
        float s = (dd==0)?xv.x:((dd==1)?xv.y:((dd==2)?xv.z:xv.w));
        const float4* w4 = (const float4*)&wl[k4*4+dd][0];
#pragma unroll
        for (int q=0;q<10;++q){
          acc[q].x += s*w4[q].x; acc[q].y += s*w4[q].y;
          acc[q].z += s*w4[q].z; acc[q].w += s*w4[q].w;
        }
      }
    }
    float4* dst = (float4*)&xp[ck%3][ptl][pbl][0];
#pragma unroll
    for (int q=0;q<10;++q) dst[q] = acc[q];
  };

  // scan-wave recurrent weights, packed (even,odd) pairs
  const float* WA = pb ? Wu : Wf;
  const float* WB = pb ? Wo : Wi;
  float wsc[24];
#pragma unroll
  for (int s=0;s<8;++s){
    int k = (j + s) & 7;
    wsc[s]    = WA[(64+k)*8 + j] * INV2PI;
    wsc[8+s]  = WB[(64+k)*8 + j] * INV2PI;
    wsc[16+s] = Wh2k[k*8 + j] * INV4PI;
  }
  f2 wA01={wsc[0],wsc[1]},  wA23={wsc[2],wsc[3]},  wA45={wsc[4],wsc[5]},  wA67={wsc[6],wsc[7]};
  f2 wB01={wsc[8],wsc[9]},  wB23={wsc[10],wsc[11]},wB45={wsc[12],wsc[13]},wB67={wsc[14],wsc[15]};
  f2 wK01={wsc[16],wsc[17]},wK23={wsc[18],wsc[19]},wK45={wsc[20],wsc[21]},wK67={wsc[22],wsc[23]};

  // activation constant pairs: slot A (f:sigmoid / u:tanh), slot B sigmoid
  f2 preP  = { pb ? 1.0f : 0.5f, 0.5f };
  f2 postMP= { pb ? 1.0f : 0.5f, 0.5f };
  f2 postBP= { pb ? 0.0f : 0.5f, 0.5f };
  // tanh13 coefficient splats
  const f2 C6 = {0.00359213f,0.00359213f};
  const f2 C5 = {-0.00886324f,-0.00886324f};
  const f2 C4 = {0.02186948f,0.02186948f};
  const f2 C3 = {-0.05396825f,-0.05396825f};
  const f2 C2 = {0.13333333f,0.13333333f};
  const f2 C1 = {-0.33333333f,-0.33333333f};
  const f2 C0 = {1.0f,1.0f};

  float h = 0.f, c = 0.f;

  __syncthreads();                     // B0: wl/bias ready

  if (wid == 1 || wid == 2){
    produce(0);
    produce(1);
  }

  __syncthreads();                     // B1: chunks 0,1 ready

  int oAB = bl*40 + (pb?16:0) + 2*j;
  int oK  = bl*40 + 32 + j;
  f2 xABq[4]; float xKq[4];
  int osto = (b0 + bl)*8 + j;
  bool st = !pb;

  if (wid == 0){
#pragma unroll
    for (int i=0;i<4;++i){
      const float* sp = &xp[0][i][0][0];
      xABq[i] = *(const f2*)&sp[oAB];
      xKq[i]  = sp[oK];
    }
  }

  // one scan step; pp = prefetch row base for step s+4
  auto STEP = [&](const float* __restrict__ pp, int u){
    float xA = xABq[u].x, xB = xABq[u].y, xK = xKq[u];
    xABq[u] = *(const f2*)&pp[oAB];
    xKq[u]  = pp[oK];

    float hr1 = DPPR(h,0x12F), hr2 = DPPR(h,0x12E), hr3 = DPPR(h,0x12D),
          hr4 = DPPR(h,0x12C), hr5 = DPPR(h,0x12B), hr6 = DPPR(h,0x12A),
          hr7 = DPPR(h,0x129);
    f2 hp0 = {h, hr1}, hp1 = {hr2, hr3}, hp2 = {hr4, hr5}, hp3 = {hr6, hr7};

    f2 accA = hp0*wA01; accA = hp1*wA23 + accA; accA = hp2*wA45 + accA; accA = hp3*wA67 + accA;
    f2 accB = hp0*wB01; accB = hp1*wB23 + accB; accB = hp2*wB45 + accB; accB = hp3*wB67 + accB;
    f2 accK = hp0*wK01; accK = hp1*wK23 + accK; accK = hp2*wK45 + accK; accK = hp3*wK67 + accK;
    float aA = accA.x + accA.y;
    float aB = accB.x + accB.y;
    float aK = accK.x + accK.y;

    float kv = fcosrev(aK - xK);
    kv *= DPPR(kv,0xB1);
    kv *= DPPR(kv,0x4E);
    { float t4a = DPPR(kv,0x124), t4b = DPPR(kv,0x12C);
      kv *= (j4 ? t4a : t4b); }
    float wk = fabsf(kv);

#define CUMQ(ZV, GQ) { \
    float zz = (ZV); \
    float pz = zz, s_; \
    s_ = DPPZ(pz,0x111); pz *= ((j>=1)? s_ : 1.0f); \
    s_ = DPPZ(pz,0x112); pz *= ((j>=2)? s_ : 1.0f); \
    s_ = DPPZ(pz,0x114); pz *= ((j>=4)? s_ : 1.0f); \
    float q = (j==0)? 1.0f : zz; \
    q *= DPPR(q,0xB1); \
    q *= DPPR(q,0x4E); \
    { float q4a = DPPR(q,0x124), q4b = DPPR(q,0x12C); q *= (j4 ? q4a : q4b); } \
    GQ = ((j==0)? q : pz) * wk; }

    float gA, gB;
    CUMQ(fcosrev(aA + xA), gA)
    CUMQ(fcosrev(aB + xB), gB)
#undef CUMQ

    // packed tanh13 core for (A,B); act = postM*t + postB
    f2 g2 = {gA, gB};
    f2 y = g2 * preP;
    f2 s2 = y * y;
    f2 p = s2*C6 + C5;
    p = p*s2 + C4;
    p = p*s2 + C3;
    p = p*s2 + C2;
    p = p*s2 + C1;
    p = p*s2 + C0;
    f2 t2 = y * p;
    f2 act = t2*postMP + postBP;
    float actA = act.x, actB = act.y;

    float gAo = DPPR(actA,0x128);
    float gBo = DPPR(actB,0x128);
    float fv = pb ? gAo  : actA;
    float uv = pb ? actA : gAo;
    float iv = pb ? gBo  : actB;
    float ov = pb ? actB : gBo;

    c = fmaf(fv, c, iv*uv);
    float c2 = c * c;
    float num = fmaf(c2, c2 + 105.0f, 945.0f);
    float den = fmaf(c2, fmaf(c2, 15.0f, 420.0f), 945.0f);
    float tch = c * num * frcp(den);
    h = ov * tch;

    if (st) out[osto] = h;
    osto += BB*8;
  };

  for (int k = 0; k < 16; ++k){
    if (wid == 0){
      const float* baseA = &xp[k%3][0][0][0];
      const float* baseB = &xp[(k+1)%3][0][0][0];   // k=15: dead loads, safe
      // steps 0..27: prefetch from current chunk
#pragma unroll 1
      for (int s4 = 0; s4 < 28; s4 += 4){
        const float* bp4 = baseA + (s4+4)*160;
#pragma unroll
        for (int u = 0; u < 4; ++u) STEP(bp4 + u*160, u);
      }
      // steps 28..31: prefetch rows 0..3 of next chunk
#pragma unroll
      for (int u = 0; u < 4; ++u) STEP(baseB + u*160, u);
    } else if (wid == 1 || wid == 2){
      if (k + 2 < 16) produce(k + 2);
    }
    __syncthreads();
  }

  if (wid == 0 && st){
    out[(size_t)TT*BB*8 + (size_t)(b0+bl)*8 + j] = h;
    out[(size_t)TT*BB*8 + (size_t)BB*8 + (size_t)(b0+bl)*8 + j] = c;
  }
}

extern "C" void kernel_launch(void* const* d_in, const int* in_sizes, int n_in,
                              void* d_out, int out_size, void* d_ws, size_t ws_size,
                              hipStream_t stream)
{
  const float* x    = (const float*)d_in[0];
  const float* Wf   = (const float*)d_in[1];
  const float* bf   = (const float*)d_in[2];
  const float* thf  = (const float*)d_in[3];
  const float* Wi   = (const float*)d_in[4];
  const float* bi   = (const float*)d_in[5];
  const float* thi  = (const float*)d_in[6];
  const float* Wu   = (const float*)d_in[7];
  const float* bu   = (const float*)d_in[8];
  const float* thu  = (const float*)d_in[9];
  const float* Wo   = (const float*)d_in[10];
  const float* bo   = (const float*)d_in[11];
  const float* tho  = (const float*)d_in[12];
  const float* Wh2k = (const float*)d_in[13];
  const float* bh2k = (const float*)d_in[14];
  const float* Wi2k = (const float*)d_in[15];
  const float* bi2k = (const float*)d_in[16];
  float* out = (float*)d_out;
  (void)d_ws; (void)ws_size; (void)in_sizes; (void)n_in; (void)out_size;

  qlstm_fused<<<BB/4, 256, 0, stream>>>(
      x, Wf,bf,thf, Wi,bi,thi, Wu,bu,thu, Wo,bo,tho,
      Wh2k, bh2k, Wi2k, bi2k, out);
}

// Round 15
// 177.111 us; speedup vs baseline: 2.3343x; 1.0289x over previous
//
#include <hip/hip_runtime.h>

#define TT 512
#define BB 1024
#define INV2PI 0.15915494309189535f
#define INV4PI 0.07957747154594767f

typedef __attribute__((ext_vector_type(2))) float f2;

__device__ __forceinline__ float frcp(float x){ return __builtin_amdgcn_rcpf(x); }
__device__ __forceinline__ float fcosrev(float r){
  float rr = r - floorf(r);
  return __builtin_amdgcn_cosf(rr);
}

#define DPPZ(v, ctrl) __int_as_float(__builtin_amdgcn_update_dpp(0, __float_as_int(v), (ctrl), 0xF, 0xF, true))
#define DPPR(v, ctrl) __int_as_float(__builtin_amdgcn_update_dpp(__float_as_int(v), __float_as_int(v), (ctrl), 0xF, 0xF, false))

// Column layout of a 40-float xpre row (same as R10/R13):
//  c in [0,32): pairIdx=c>>1 (j=pairIdx&7, pb=pairIdx>>3), slot=c&1, g=2*pb+slot
//               value = (x@Wg[:64] + bg + thg) * INV2PI
//  c in [32,40): j=c-32, value = (x@Wi2k + bi2k - bh2k) * INV4PI

// Prep: write pre-scaled weight matrix [64][40] into d_ws (global).
// Producers then read it with WAVE-UNIFORM indices -> compiler emits s_load
// (scalar pipe), removing ~1280 ds_read_b128/chunk of DS-pipe pressure.
__global__ __launch_bounds__(256,1) void qlstm_prep(
    const float* __restrict__ Wf, const float* __restrict__ Wi,
    const float* __restrict__ Wu, const float* __restrict__ Wo,
    const float* __restrict__ Wi2k,
    float* __restrict__ gw)
{
  int idx = blockIdx.x*256 + threadIdx.x;
  if (idx >= 64*40) return;
  int d = idx / 40, cc = idx - d*40;
  float v;
  if (cc < 32){
    int pi = cc >> 1, slot = cc & 1;
    int jj = pi & 7, pbc = pi >> 3;
    int g = 2*pbc + slot;
    const float* W = (g==0)?Wf:((g==1)?Wi:((g==2)?Wu:Wo));
    v = W[d*8+jj] * INV2PI;
  } else {
    v = Wi2k[d*8 + (cc-32)] * INV4PI;
  }
  gw[idx] = v;
}

// Fused: wave 0 scans 4 elements (R13 verbatim); waves 1-2 project 32-step
// chunks into triple-buffered LDS (weights from global/scalar pipe, x from
// VMEM), 2 chunks ahead; wave 3 barrier-only.
__global__ __launch_bounds__(256,1) void qlstm_fused(
    const float* __restrict__ x,
    const float* __restrict__ gw,
    const float* __restrict__ Wf, const float* __restrict__ bfp, const float* __restrict__ thf,
    const float* __restrict__ Wi, const float* __restrict__ bip, const float* __restrict__ thi,
    const float* __restrict__ Wu, const float* __restrict__ bup, const float* __restrict__ thu,
    const float* __restrict__ Wo, const float* __restrict__ bop, const float* __restrict__ tho,
    const float* __restrict__ Wh2k, const float* __restrict__ bh2k,
    const float* __restrict__ Wi2k, const float* __restrict__ bi2k,
    float* __restrict__ out)
{
  __shared__ float bias[40];
  __shared__ float xp[3][32][4][40];   // [buf][t_local][b_local][col]

  int tid = threadIdx.x;
  int b0 = blockIdx.x * 4;

  // ---- fill bias LDS ----
  if (tid < 40){
    int cc = tid; float v;
    if (cc < 32){
      int pi = cc >> 1, slot = cc & 1;
      int jj = pi & 7, pbc = pi >> 3;
      int g = 2*pbc + slot;
      const float* bp = (g==0)?bfp:((g==1)?bip:((g==2)?bup:bop));
      const float* tp = (g==0)?thf:((g==1)?thi:((g==2)?thu:tho));
      v = (bp[jj] + tp[jj]) * INV2PI;
    } else {
      v = (bi2k[cc-32] - bh2k[cc-32]) * INV4PI;
    }
    bias[cc] = v;
  }

  int wid = tid >> 6;
  int j  = tid & 7;
  bool pb = (tid & 8) != 0;
  bool j4 = (j & 4) != 0;
  int bl = (tid >> 4) & 3;

  // producer lane mapping (waves 1-2)
  int plane = tid - 64;                // 0..127
  int ptl = plane >> 2, pbl = plane & 3;

  auto produce = [&](int ck){
    int t = ck*32 + ptl;
    const float4* xr = (const float4*)(x + ((size_t)t*BB + b0 + pbl)*64);
    float4 acc[10];
    const float4* b4 = (const float4*)bias;
#pragma unroll
    for (int q=0;q<10;++q) acc[q] = b4[q];
#pragma unroll 1
    for (int k4=0;k4<16;++k4){
      float4 xv = xr[k4];
#pragma unroll
      for (int dd=0; dd<4; ++dd){
        float s = (dd==0)?xv.x:((dd==1)?xv.y:((dd==2)?xv.z:xv.w));
        // wave-uniform index -> scalar loads (s_load), not DS
        const float4* w4 = (const float4*)&gw[(k4*4+dd)*40];
#pragma unroll
        for (int q=0;q<10;++q){
          acc[q].x += s*w4[q].x; acc[q].y += s*w4[q].y;
          acc[q].z += s*w4[q].z; acc[q].w += s*w4[q].w;
        }
      }
    }
    float4* dst = (float4*)&xp[ck%3][ptl][pbl][0];
#pragma unroll
    for (int q=0;q<10;++q) dst[q] = acc[q];
  };

  // scan-wave recurrent weights, packed (even,odd) pairs
  const float* WA = pb ? Wu : Wf;
  const float* WB = pb ? Wo : Wi;
  float wsc[24];
#pragma unroll
  for (int s=0;s<8;++s){
    int k = (j + s) & 7;
    wsc[s]    = WA[(64+k)*8 + j] * INV2PI;
    wsc[8+s]  = WB[(64+k)*8 + j] * INV2PI;
    wsc[16+s] = Wh2k[k*8 + j] * INV4PI;
  }
  f2 wA01={wsc[0],wsc[1]},  wA23={wsc[2],wsc[3]},  wA45={wsc[4],wsc[5]},  wA67={wsc[6],wsc[7]};
  f2 wB01={wsc[8],wsc[9]},  wB23={wsc[10],wsc[11]},wB45={wsc[12],wsc[13]},wB67={wsc[14],wsc[15]};
  f2 wK01={wsc[16],wsc[17]},wK23={wsc[18],wsc[19]},wK45={wsc[20],wsc[21]},wK67={wsc[22],wsc[23]};

  // activation constant pairs: slot A (f:sigmoid / u:tanh), slot B sigmoid
  f2 preP  = { pb ? 1.0f : 0.5f, 0.5f };
  f2 postMP= { pb ? 1.0f : 0.5f, 0.5f };
  f2 postBP= { pb ? 0.0f : 0.5f, 0.5f };
  // tanh13 coefficient splats
  const f2 C6 = {0.00359213f,0.00359213f};
  const f2 C5 = {-0.00886324f,-0.00886324f};
  const f2 C4 = {0.02186948f,0.02186948f};
  const f2 C3 = {-0.05396825f,-0.05396825f};
  const f2 C2 = {0.13333333f,0.13333333f};
  const f2 C1 = {-0.33333333f,-0.33333333f};
  const f2 C0 = {1.0f,1.0f};

  float h = 0.f, c = 0.f;

  __syncthreads();                     // B0: bias ready

  if (wid == 1 || wid == 2){
    produce(0);
    produce(1);
  }

  __syncthreads();                     // B1: chunks 0,1 ready

  int oAB = bl*40 + (pb?16:0) + 2*j;
  int oK  = bl*40 + 32 + j;
  f2 xABq[4]; float xKq[4];
  int osto = (b0 + bl)*8 + j;
  bool st = !pb;

  if (wid == 0){
#pragma unroll
    for (int i=0;i<4;++i){
      const float* sp = &xp[0][i][0][0];
      xABq[i] = *(const f2*)&sp[oAB];
      xKq[i]  = sp[oK];
    }
  }

  // one scan step; pp = prefetch row base for step s+4 (R13 verbatim)
  auto STEP = [&](const float* __restrict__ pp, int u){
    float xA = xABq[u].x, xB = xABq[u].y, xK = xKq[u];
    xABq[u] = *(const f2*)&pp[oAB];
    xKq[u]  = pp[oK];

    float hr1 = DPPR(h,0x12F), hr2 = DPPR(h,0x12E), hr3 = DPPR(h,0x12D),
          hr4 = DPPR(h,0x12C), hr5 = DPPR(h,0x12B), hr6 = DPPR(h,0x12A),
          hr7 = DPPR(h,0x129);
    f2 hp0 = {h, hr1}, hp1 = {hr2, hr3}, hp2 = {hr4, hr5}, hp3 = {hr6, hr7};

    f2 accA = hp0*wA01; accA = hp1*wA23 + accA; accA = hp2*wA45 + accA; accA = hp3*wA67 + accA;
    f2 accB = hp0*wB01; accB = hp1*wB23 + accB; accB = hp2*wB45 + accB; accB = hp3*wB67 + accB;
    f2 accK = hp0*wK01; accK = hp1*wK23 + accK; accK = hp2*wK45 + accK; accK = hp3*wK67 + accK;
    float aA = accA.x + accA.y;
    float aB = accB.x + accB.y;
    float aK = accK.x + accK.y;

    float kv = fcosrev(aK - xK);
    kv *= DPPR(kv,0xB1);
    kv *= DPPR(kv,0x4E);
    { float t4a = DPPR(kv,0x124), t4b = DPPR(kv,0x12C);
      kv *= (j4 ? t4a : t4b); }
    float wk = fabsf(kv);

#define CUMQ(ZV, GQ) { \
    float zz = (ZV); \
    float pz = zz, s_; \
    s_ = DPPZ(pz,0x111); pz *= ((j>=1)? s_ : 1.0f); \
    s_ = DPPZ(pz,0x112); pz *= ((j>=2)? s_ : 1.0f); \
    s_ = DPPZ(pz,0x114); pz *= ((j>=4)? s_ : 1.0f); \
    float q = (j==0)? 1.0f : zz; \
    q *= DPPR(q,0xB1); \
    q *= DPPR(q,0x4E); \
    { float q4a = DPPR(q,0x124), q4b = DPPR(q,0x12C); q *= (j4 ? q4a : q4b); } \
    GQ = ((j==0)? q : pz) * wk; }

    float gA, gB;
    CUMQ(fcosrev(aA + xA), gA)
    CUMQ(fcosrev(aB + xB), gB)
#undef CUMQ

    // packed tanh13 core for (A,B); act = postM*t + postB
    f2 g2 = {gA, gB};
    f2 y = g2 * preP;
    f2 s2 = y * y;
    f2 p = s2*C6 + C5;
    p = p*s2 + C4;
    p = p*s2 + C3;
    p = p*s2 + C2;
    p = p*s2 + C1;
    p = p*s2 + C0;
    f2 t2 = y * p;
    f2 act = t2*postMP + postBP;
    float actA = act.x, actB = act.y;

    float gAo = DPPR(actA,0x128);
    float gBo = DPPR(actB,0x128);
    float fv = pb ? gAo  : actA;
    float uv = pb ? actA : gAo;
    float iv = pb ? gBo  : actB;
    float ov = pb ? actB : gBo;

    c = fmaf(fv, c, iv*uv);
    float c2 = c * c;
    float num = fmaf(c2, c2 + 105.0f, 945.0f);
    float den = fmaf(c2, fmaf(c2, 15.0f, 420.0f), 945.0f);
    float tch = c * num * frcp(den);
    h = ov * tch;

    if (st) out[osto] = h;
    osto += BB*8;
  };

  for (int k = 0; k < 16; ++k){
    if (wid == 0){
      const float* baseA = &xp[k%3][0][0][0];
      const float* baseB = &xp[(k+1)%3][0][0][0];   // k=15: dead loads, safe
      // steps 0..27: prefetch from current chunk
#pragma unroll 1
      for (int s4 = 0; s4 < 28; s4 += 4){
        const float* bp4 = baseA + (s4+4)*160;
#pragma unroll
        for (int u = 0; u < 4; ++u) STEP(bp4 + u*160, u);
      }
      // steps 28..31: prefetch rows 0..3 of next chunk
#pragma unroll
      for (int u = 0; u < 4; ++u) STEP(baseB + u*160, u);
    } else if (wid == 1 || wid == 2){
      if (k + 2 < 16) produce(k + 2);
    }
    __syncthreads();
  }

  if (wid == 0 && st){
    out[(size_t)TT*BB*8 + (size_t)(b0+bl)*8 + j] = h;
    out[(size_t)TT*BB*8 + (size_t)BB*8 + (size_t)(b0+bl)*8 + j] = c;
  }
}

extern "C" void kernel_launch(void* const* d_in, const int* in_sizes, int n_in,
                              void* d_out, int out_size, void* d_ws, size_t ws_size,
                              hipStream_t stream)
{
  const float* x    = (const float*)d_in[0];
  const float* Wf   = (const float*)d_in[1];
  const float* bf   = (const float*)d_in[2];
  const float* thf  = (const float*)d_in[3];
  const float* Wi   = (const float*)d_in[4];
  const float* bi   = (const float*)d_in[5];
  const float* thi  = (const float*)d_in[6];
  const float* Wu   = (const float*)d_in[7];
  const float* bu   = (const float*)d_in[8];
  const float* thu  = (const float*)d_in[9];
  const float* Wo   = (const float*)d_in[10];
  const float* bo   = (const float*)d_in[11];
  const float* tho  = (const float*)d_in[12];
  const float* Wh2k = (const float*)d_in[13];
  const float* bh2k = (const float*)d_in[14];
  const float* Wi2k = (const float*)d_in[15];
  const float* bi2k = (const float*)d_in[16];
  float* out = (float*)d_out;
  float* gw  = (float*)d_ws;           // [64][40] pre-scaled weights
  (void)ws_size; (void)in_sizes; (void)n_in; (void)out_size;

  qlstm_prep<<<10, 256, 0, stream>>>(Wf, Wi, Wu, Wo, Wi2k, gw);
  qlstm_fused<<<BB/4, 256, 0, stream>>>(
      x, gw, Wf,bf,thf, Wi,bi,thi, Wu,bu,thu, Wo,bo,tho,
      Wh2k, bh2k, Wi2k, bi2k, out);
}

// Round 16
// 164.898 us; speedup vs baseline: 2.5072x; 1.0741x over previous
//
#include <hip/hip_runtime.h>

#define TT 512
#define BB 1024
#define INV2PI 0.15915494309189535f
#define INV4PI 0.07957747154594767f

typedef __attribute__((ext_vector_type(2))) float f2;

__device__ __forceinline__ float frcp(float x){ return __builtin_amdgcn_rcpf(x); }
// cos(2*pi*r): v_fract_f32 (single-op range reduction) + V_COS
__device__ __forceinline__ float fcosrev(float r){
  return __builtin_amdgcn_cosf(__builtin_amdgcn_fractf(r));
}

#define DPPZ(v, ctrl) __int_as_float(__builtin_amdgcn_update_dpp(0, __float_as_int(v), (ctrl), 0xF, 0xF, true))
#define DPPR(v, ctrl) __int_as_float(__builtin_amdgcn_update_dpp(__float_as_int(v), __float_as_int(v), (ctrl), 0xF, 0xF, false))

// Column layout of a 40-float xpre row (same as R10/R13/R15):
//  c in [0,32): pairIdx=c>>1 (j=pairIdx&7, pb=pairIdx>>3), slot=c&1, g=2*pb+slot
//               value = (x@Wg[:64] + bg + thg) * INV2PI
//  c in [32,40): j=c-32, value = (x@Wi2k + bi2k - bh2k) * INV4PI

// Prep: pre-scaled weight matrix [64][40] into d_ws (global). Producers read
// it with wave-uniform indices -> scalar pipe (s_load), zero DS pressure.
__global__ __launch_bounds__(256,1) void qlstm_prep(
    const float* __restrict__ Wf, const float* __restrict__ Wi,
    const float* __restrict__ Wu, const float* __restrict__ Wo,
    const float* __restrict__ Wi2k,
    float* __restrict__ gw)
{
  int idx = blockIdx.x*256 + threadIdx.x;
  if (idx >= 64*40) return;
  int d = idx / 40, cc = idx - d*40;
  float v;
  if (cc < 32){
    int pi = cc >> 1, slot = cc & 1;
    int jj = pi & 7, pbc = pi >> 3;
    int g = 2*pbc + slot;
    const float* W = (g==0)?Wf:((g==1)?Wi:((g==2)?Wu:Wo));
    v = W[d*8+jj] * INV2PI;
  } else {
    v = Wi2k[d*8 + (cc-32)] * INV4PI;
  }
  gw[idx] = v;
}

// Fused: wave 0 scans 4 elements; waves 1-2 project 32-step chunks into
// triple-buffered LDS (weights via scalar pipe), 2 chunks ahead; wave 3
// barrier-only.
__global__ __launch_bounds__(256,1) void qlstm_fused(
    const float* __restrict__ x,
    const float* __restrict__ gw,
    const float* __restrict__ Wf, const float* __restrict__ bfp, const float* __restrict__ thf,
    const float* __restrict__ Wi, const float* __restrict__ bip, const float* __restrict__ thi,
    const float* __restrict__ Wu, const float* __restrict__ bup, const float* __restrict__ thu,
    const float* __restrict__ Wo, const float* __restrict__ bop, const float* __restrict__ tho,
    const float* __restrict__ Wh2k, const float* __restrict__ bh2k,
    const float* __restrict__ Wi2k, const float* __restrict__ bi2k,
    float* __restrict__ out)
{
  __shared__ float bias[40];
  __shared__ float xp[3][32][4][40];   // [buf][t_local][b_local][col]

  int tid = threadIdx.x;
  int b0 = blockIdx.x * 4;

  // ---- fill bias LDS ----
  if (tid < 40){
    int cc = tid; float v;
    if (cc < 32){
      int pi = cc >> 1, slot = cc & 1;
      int jj = pi & 7, pbc = pi >> 3;
      int g = 2*pbc + slot;
      const float* bp = (g==0)?bfp:((g==1)?bip:((g==2)?bup:bop));
      const float* tp = (g==0)?thf:((g==1)?thi:((g==2)?thu:tho));
      v = (bp[jj] + tp[jj]) * INV2PI;
    } else {
      v = (bi2k[cc-32] - bh2k[cc-32]) * INV4PI;
    }
    bias[cc] = v;
  }

  int wid = tid >> 6;
  int j  = tid & 7;
  bool pb = (tid & 8) != 0;
  bool j4 = (j & 4) != 0;
  int bl = (tid >> 4) & 3;

  // producer lane mapping (waves 1-2)
  int plane = tid - 64;                // 0..127
  int ptl = plane >> 2, pbl = plane & 3;

  auto produce = [&](int ck){
    int t = ck*32 + ptl;
    const float4* xr = (const float4*)(x + ((size_t)t*BB + b0 + pbl)*64);
    float4 acc[10];
    const float4* b4 = (const float4*)bias;
#pragma unroll
    for (int q=0;q<10;++q) acc[q] = b4[q];
#pragma unroll 1
    for (int k4=0;k4<16;++k4){
      float4 xv = xr[k4];
#pragma unroll
      for (int dd=0; dd<4; ++dd){
        float s = (dd==0)?xv.x:((dd==1)?xv.y:((dd==2)?xv.z:xv.w));
        // wave-uniform index -> scalar loads (s_load), not DS
        const float4* w4 = (const float4*)&gw[(k4*4+dd)*40];
#pragma unroll
        for (int q=0;q<10;++q){
          acc[q].x += s*w4[q].x; acc[q].y += s*w4[q].y;
          acc[q].z += s*w4[q].z; acc[q].w += s*w4[q].w;
        }
      }
    }
    float4* dst = (float4*)&xp[ck%3][ptl][pbl][0];
#pragma unroll
    for (int q=0;q<10;++q) dst[q] = acc[q];
  };

  // scan-wave recurrent weights, packed (even,odd) pairs
  const float* WA = pb ? Wu : Wf;
  const float* WB = pb ? Wo : Wi;
  float wsc[24];
#pragma unroll
  for (int s=0;s<8;++s){
    int k = (j + s) & 7;
    wsc[s]    = WA[(64+k)*8 + j] * INV2PI;
    wsc[8+s]  = WB[(64+k)*8 + j] * INV2PI;
    wsc[16+s] = Wh2k[k*8 + j] * INV4PI;
  }
  f2 wA01={wsc[0],wsc[1]},  wA23={wsc[2],wsc[3]},  wA45={wsc[4],wsc[5]},  wA67={wsc[6],wsc[7]};
  f2 wB01={wsc[8],wsc[9]},  wB23={wsc[10],wsc[11]},wB45={wsc[12],wsc[13]},wB67={wsc[14],wsc[15]};
  f2 wK01={wsc[16],wsc[17]},wK23={wsc[18],wsc[19]},wK45={wsc[20],wsc[21]},wK67={wsc[22],wsc[23]};

  // wk pre-scale factors (fold the tanh-core input scale into wk):
  float preA = pb ? 1.0f : 0.5f;       // slot A: u->tanh(y), f->sigmoid(y/2)
  // post constants
  f2 postMP= { pb ? 1.0f : 0.5f, 0.5f };
  f2 postBP= { pb ? 0.0f : 0.5f, 0.5f };
  // tanh13 coefficient splats
  const f2 C6 = {0.00359213f,0.00359213f};
  const f2 C5 = {-0.00886324f,-0.00886324f};
  const f2 C4 = {0.02186948f,0.02186948f};
  const f2 C3 = {-0.05396825f,-0.05396825f};
  const f2 C2 = {0.13333333f,0.13333333f};
  const f2 C1 = {-0.33333333f,-0.33333333f};
  const f2 C0 = {1.0f,1.0f};

  float h = 0.f, c = 0.f;

  __syncthreads();                     // B0: bias ready

  if (wid == 1 || wid == 2){
    produce(0);
    produce(1);
  }

  __syncthreads();                     // B1: chunks 0,1 ready

  int oAB = bl*40 + (pb?16:0) + 2*j;
  int oK  = bl*40 + 32 + j;
  f2 xABq[4]; float xKq[4];
  int osto = (b0 + bl)*8 + j;

  if (wid == 0){
#pragma unroll
    for (int i=0;i<4;++i){
      const float* sp = &xp[0][i][0][0];
      xABq[i] = *(const f2*)&sp[oAB];
      xKq[i]  = sp[oK];
    }
  }

  // one scan step; pp = prefetch row base for step s+4
  auto STEP = [&](const float* __restrict__ pp, int u){
    float xA = xABq[u].x, xB = xABq[u].y, xK = xKq[u];
    xABq[u] = *(const f2*)&pp[oAB];
    xKq[u]  = pp[oK];

    float hr1 = DPPR(h,0x12F), hr2 = DPPR(h,0x12E), hr3 = DPPR(h,0x12D),
          hr4 = DPPR(h,0x12C), hr5 = DPPR(h,0x12B), hr6 = DPPR(h,0x12A),
          hr7 = DPPR(h,0x129);
    f2 hp0 = {h, hr1}, hp1 = {hr2, hr3}, hp2 = {hr4, hr5}, hp3 = {hr6, hr7};

    f2 accA = hp0*wA01; accA = hp1*wA23 + accA; accA = hp2*wA45 + accA; accA = hp3*wA67 + accA;
    f2 accB = hp0*wB01; accB = hp1*wB23 + accB; accB = hp2*wB45 + accB; accB = hp3*wB67 + accB;
    f2 accK = hp0*wK01; accK = hp1*wK23 + accK; accK = hp2*wK45 + accK; accK = hp3*wK67 + accK;
    float aA = accA.x + accA.y;
    float aB = accB.x + accB.y;
    float aK = accK.x + accK.y;

    float kv = fcosrev(aK - xK);
    kv *= DPPR(kv,0xB1);
    kv *= DPPR(kv,0x4E);
    { float t4a = DPPR(kv,0x124), t4b = DPPR(kv,0x12C);
      kv *= (j4 ? t4a : t4b); }
    float wk = fabsf(kv);
    float wkA = wk * preA;             // folded tanh-core input scales
    float wkB = wk * 0.5f;

#define CUMQ(ZV, WKX, GQ) { \
    float zz = (ZV); \
    float pz = zz, s_; \
    s_ = DPPZ(pz,0x111); pz *= ((j>=1)? s_ : 1.0f); \
    s_ = DPPZ(pz,0x112); pz *= ((j>=2)? s_ : 1.0f); \
    s_ = DPPZ(pz,0x114); pz *= ((j>=4)? s_ : 1.0f); \
    float q = (j==0)? 1.0f : zz; \
    q *= DPPR(q,0xB1); \
    q *= DPPR(q,0x4E); \
    { float q4a = DPPR(q,0x124), q4b = DPPR(q,0x12C); q *= (j4 ? q4a : q4b); } \
    GQ = ((j==0)? q : pz) * (WKX); }

    float yA, yB;
    CUMQ(fcosrev(aA + xA), wkA, yA)
    CUMQ(fcosrev(aB + xB), wkB, yB)
#undef CUMQ

    // packed tanh13 core on pre-scaled inputs; act = postM*t + postB
    f2 y = {yA, yB};
    f2 s2 = y * y;
    f2 p = s2*C6 + C5;
    p = p*s2 + C4;
    p = p*s2 + C3;
    p = p*s2 + C2;
    p = p*s2 + C1;
    p = p*s2 + C0;
    f2 t2 = y * p;
    f2 act = t2*postMP + postBP;
    float actA = act.x, actB = act.y;

    float gAo = DPPR(actA,0x128);
    float gBo = DPPR(actB,0x128);
    float fv = pb ? gAo  : actA;
    float uv = pb ? actA : gAo;
    float iv = pb ? gBo  : actB;
    float ov = pb ? actB : gBo;

    c = fmaf(fv, c, iv*uv);
    float c2 = c * c;
    float num = fmaf(c2, c2 + 105.0f, 945.0f);
    float den = fmaf(c2, fmaf(c2, 15.0f, 420.0f), 945.0f);
    float tch = c * num * frcp(den);
    h = ov * tch;

    // unconditional store: pb pair lanes write the same addr with the same
    // value (h replicated) -> no exec-mask dance
    out[osto] = h;
    osto += BB*8;
  };

  for (int k = 0; k < 16; ++k){
    if (wid == 0){
      const float* baseA = &xp[k%3][0][0][0];
      const float* baseB = &xp[(k+1)%3][0][0][0];   // k=15: dead loads, safe
      // steps 0..27: prefetch from current chunk
#pragma unroll 1
      for (int s4 = 0; s4 < 28; s4 += 4){
        const float* bp4 = baseA + (s4+4)*160;
#pragma unroll
        for (int u = 0; u < 4; ++u) STEP(bp4 + u*160, u);
      }
      // steps 28..31: prefetch rows 0..3 of next chunk
#pragma unroll
      for (int u = 0; u < 4; ++u) STEP(baseB + u*160, u);
    } else if (wid == 1 || wid == 2){
      if (k + 2 < 16) produce(k + 2);
    }
    __syncthreads();
  }

  if (wid == 0){
    out[(size_t)TT*BB*8 + (size_t)(b0+bl)*8 + j] = h;
    out[(size_t)TT*BB*8 + (size_t)BB*8 + (size_t)(b0+bl)*8 + j] = c;
  }
}

extern "C" void kernel_launch(void* const* d_in, const int* in_sizes, int n_in,
                              void* d_out, int out_size, void* d_ws, size_t ws_size,
                              hipStream_t stream)
{
  const float* x    = (const float*)d_in[0];
  const float* Wf   = (const float*)d_in[1];
  const float* bf   = (const float*)d_in[2];
  const float* thf  = (const float*)d_in[3];
  const float* Wi   = (const float*)d_in[4];
  const float* bi   = (const float*)d_in[5];
  const float* thi  = (const float*)d_in[6];
  const float* Wu   = (const float*)d_in[7];
  const float* bu   = (const float*)d_in[8];
  const float* thu  = (const float*)d_in[9];
  const float* Wo   = (const float*)d_in[10];
  const float* bo   = (const float*)d_in[11];
  const float* tho  = (const float*)d_in[12];
  const float* Wh2k = (const float*)d_in[13];
  const float* bh2k = (const float*)d_in[14];
  const float* Wi2k = (const float*)d_in[15];
  const float* bi2k = (const float*)d_in[16];
  float* out = (float*)d_out;
  float* gw  = (float*)d_ws;           // [64][40] pre-scaled weights
  (void)ws_size; (void)in_sizes; (void)n_in; (void)out_size;

  qlstm_prep<<<10, 256, 0, stream>>>(Wf, Wi, Wu, Wo, Wi2k, gw);
  qlstm_fused<<<BB/4, 256, 0, stream>>>(
      x, gw, Wf,bf,thf, Wi,bi,thi, Wu,bu,thu, Wo,bo,tho,
      Wh2k, bh2k, Wi2k, bi2k, out);
}

// Round 17
// 162.840 us; speedup vs baseline: 2.5389x; 1.0126x over previous
//
#include <hip/hip_runtime.h>

#define TT 512
#define BB 1024
#define INV2PI 0.15915494309189535f
#define INV4PI 0.07957747154594767f

typedef __attribute__((ext_vector_type(2))) float f2;

__device__ __forceinline__ float frcp(float x){ return __builtin_amdgcn_rcpf(x); }
// cos(2*pi*r): v_fract_f32 (single-op range reduction) + V_COS
__device__ __forceinline__ float fcosrev(float r){
  return __builtin_amdgcn_cosf(__builtin_amdgcn_fractf(r));
}

#define DPPR(v, ctrl) __int_as_float(__builtin_amdgcn_update_dpp(__float_as_int(v), __float_as_int(v), (ctrl), 0xF, 0xF, false))
// row_shr with old=1.0 for lanes whose source falls off the 16-row edge.
// VALID ONLY when group boundaries coincide with row boundaries (interleaved
// pb layout: j-group = stride-2 lanes, so shr:2/4/8 invalid sets == mask sets).
#define DPP1(v, ctrl) __int_as_float(__builtin_amdgcn_update_dpp(0x3f800000, __float_as_int(v), (ctrl), 0xF, 0xF, false))

// INTERLEAVED lane mapping (new in R17): lane l: pb = l&1, j = (l>>1)&7.
// Column layout of a 40-float xpre row: c in [0,32): pairIdx = c>>1 = 2*j+pb,
// slot = c&1, gate g = 2*pb+slot (pb=0:{f,i}, pb=1:{u,o});
// value = (x@Wg[:64]+bg+thg)*INV2PI.  c in [32,40): unit j=c-32,
// value = (x@Wi2k+bi2k-bh2k)*INV4PI.

// Prep: pre-scaled weight matrix [64][40] into d_ws (global). Producers read
// it with wave-uniform indices -> scalar pipe (s_load), zero DS pressure.
__global__ __launch_bounds__(256,1) void qlstm_prep(
    const float* __restrict__ Wf, const float* __restrict__ Wi,
    const float* __restrict__ Wu, const float* __restrict__ Wo,
    const float* __restrict__ Wi2k,
    float* __restrict__ gw)
{
  int idx = blockIdx.x*256 + threadIdx.x;
  if (idx >= 64*40) return;
  int d = idx / 40, cc = idx - d*40;
  float v;
  if (cc < 32){
    int pi = cc >> 1, slot = cc & 1;
    int jj = pi >> 1, pbc = pi & 1;          // interleaved decode
    int g = 2*pbc + slot;
    const float* W = (g==0)?Wf:((g==1)?Wi:((g==2)?Wu:Wo));
    v = W[d*8+jj] * INV2PI;
  } else {
    v = Wi2k[d*8 + (cc-32)] * INV4PI;
  }
  gw[idx] = v;
}

// Fused: wave 0 scans 4 elements; waves 1-2 project 32-step chunks into
// triple-buffered LDS (weights via scalar pipe), 2 chunks ahead; wave 3
// barrier-only.
__global__ __launch_bounds__(256,1) void qlstm_fused(
    const float* __restrict__ x,
    const float* __restrict__ gw,
    const float* __restrict__ Wf, const float* __restrict__ bfp, const float* __restrict__ thf,
    const float* __restrict__ Wi, const float* __restrict__ bip, const float* __restrict__ thi,
    const float* __restrict__ Wu, const float* __restrict__ bup, const float* __restrict__ thu,
    const float* __restrict__ Wo, const float* __restrict__ bop, const float* __restrict__ tho,
    const float* __restrict__ Wh2k, const float* __restrict__ bh2k,
    const float* __restrict__ Wi2k, const float* __restrict__ bi2k,
    float* __restrict__ out)
{
  __shared__ float bias[40];
  __shared__ float xp[3][32][4][40];   // [buf][t_local][b_local][col]

  int tid = threadIdx.x;
  int b0 = blockIdx.x * 4;

  // ---- fill bias LDS (interleaved decode) ----
  if (tid < 40){
    int cc = tid; float v;
    if (cc < 32){
      int pi = cc >> 1, slot = cc & 1;
      int jj = pi >> 1, pbc = pi & 1;
      int g = 2*pbc + slot;
      const float* bp = (g==0)?bfp:((g==1)?bip:((g==2)?bup:bop));
      const float* tp = (g==0)?thf:((g==1)?thi:((g==2)?thu:tho));
      v = (bp[jj] + tp[jj]) * INV2PI;
    } else {
      v = (bi2k[cc-32] - bh2k[cc-32]) * INV4PI;
    }
    bias[cc] = v;
  }

  int wid = tid >> 6;
  bool pb = (tid & 1) != 0;            // interleaved: pb = bit0
  int j  = (tid >> 1) & 7;             // unit = bits1-3
  bool j4 = (tid & 4) != 0;            // xor4-select bit (same lanes as before)
  int bl = (tid >> 4) & 3;

  // producer lane mapping (waves 1-2) — unchanged
  int plane = tid - 64;                // 0..127
  int ptl = plane >> 2, pbl = plane & 3;

  auto produce = [&](int ck){
    int t = ck*32 + ptl;
    const float4* xr = (const float4*)(x + ((size_t)t*BB + b0 + pbl)*64);
    float4 acc[10];
    const float4* b4 = (const float4*)bias;
#pragma unroll
    for (int q=0;q<10;++q) acc[q] = b4[q];
#pragma unroll 1
    for (int k4=0;k4<16;++k4){
      float4 xv = xr[k4];
#pragma unroll
      for (int dd=0; dd<4; ++dd){
        float s = (dd==0)?xv.x:((dd==1)?xv.y:((dd==2)?xv.z:xv.w));
        // wave-uniform index -> scalar loads (s_load), not DS
        const float4* w4 = (const float4*)&gw[(k4*4+dd)*40];
#pragma unroll
        for (int q=0;q<10;++q){
          acc[q].x += s*w4[q].x; acc[q].y += s*w4[q].y;
          acc[q].z += s*w4[q].z; acc[q].w += s*w4[q].w;
        }
      }
    }
    float4* dst = (float4*)&xp[ck%3][ptl][pbl][0];
#pragma unroll
    for (int q=0;q<10;++q) dst[q] = acc[q];
  };

  // scan-wave recurrent weights, packed (even,odd) pairs
  const float* WA = pb ? Wu : Wf;
  const float* WB = pb ? Wo : Wi;
  float wsc[24];
#pragma unroll
  for (int s=0;s<8;++s){
    int k = (j + s) & 7;
    wsc[s]    = WA[(64+k)*8 + j] * INV2PI;
    wsc[8+s]  = WB[(64+k)*8 + j] * INV2PI;
    wsc[16+s] = Wh2k[k*8 + j] * INV4PI;
  }
  f2 wA01={wsc[0],wsc[1]},  wA23={wsc[2],wsc[3]},  wA45={wsc[4],wsc[5]},  wA67={wsc[6],wsc[7]};
  f2 wB01={wsc[8],wsc[9]},  wB23={wsc[10],wsc[11]},wB45={wsc[12],wsc[13]},wB67={wsc[14],wsc[15]};
  f2 wK01={wsc[16],wsc[17]},wK23={wsc[18],wsc[19]},wK45={wsc[20],wsc[21]},wK67={wsc[22],wsc[23]};

  float preA = pb ? 1.0f : 0.5f;       // folded tanh-core input scale (slot A)
  f2 postMP= { pb ? 1.0f : 0.5f, 0.5f };
  f2 postBP= { pb ? 0.0f : 0.5f, 0.5f };
  const f2 C6 = {0.00359213f,0.00359213f};
  const f2 C5 = {-0.00886324f,-0.00886324f};
  const f2 C4 = {0.02186948f,0.02186948f};
  const f2 C3 = {-0.05396825f,-0.05396825f};
  const f2 C2 = {0.13333333f,0.13333333f};
  const f2 C1 = {-0.33333333f,-0.33333333f};
  const f2 C0 = {1.0f,1.0f};

  float h = 0.f, c = 0.f;

  __syncthreads();                     // B0: bias ready

  if (wid == 1 || wid == 2){
    produce(0);
    produce(1);
  }

  __syncthreads();                     // B1: chunks 0,1 ready

  int oAB = bl*40 + 2*(tid & 15);      // pairIdx = lane&15 = 2*j+pb
  int oK  = bl*40 + 32 + j;
  f2 xABq[4]; float xKq[4];
  int osto = (b0 + bl)*8 + j;

  if (wid == 0){
#pragma unroll
    for (int i=0;i<4;++i){
      const float* sp = &xp[0][i][0][0];
      xABq[i] = *(const f2*)&sp[oAB];
      xKq[i]  = sp[oK];
    }
  }

  // one scan step; pp = prefetch row base for step s+4
  auto STEP = [&](const float* __restrict__ pp, int u){
    float xA = xABq[u].x, xB = xABq[u].y, xK = xKq[u];
    xABq[u] = *(const f2*)&pp[oAB];
    xKq[u]  = pp[oK];

    // rotations: lane l needs h[(j+s)&7] = lane (l+2s)&15 -> ror:(16-2s)
    float hr1 = DPPR(h,0x12E), hr2 = DPPR(h,0x12C), hr3 = DPPR(h,0x12A),
          hr4 = DPPR(h,0x128), hr5 = DPPR(h,0x126), hr6 = DPPR(h,0x124),
          hr7 = DPPR(h,0x122);
    f2 hp0 = {h, hr1}, hp1 = {hr2, hr3}, hp2 = {hr4, hr5}, hp3 = {hr6, hr7};

    f2 accA = hp0*wA01; accA = hp1*wA23 + accA; accA = hp2*wA45 + accA; accA = hp3*wA67 + accA;
    f2 accB = hp0*wB01; accB = hp1*wB23 + accB; accB = hp2*wB45 + accB; accB = hp3*wB67 + accB;
    f2 accK = hp0*wK01; accK = hp1*wK23 + accK; accK = hp2*wK45 + accK; accK = hp3*wK67 + accK;
    float aA = accA.x + accA.y;
    float aB = accB.x + accB.y;
    float aK = accK.x + accK.y;

    // kv tree over the j-group: xor j-bits = lane-xor {2,4,8}
    float kv = fcosrev(aK - xK);
    kv *= DPPR(kv,0x4E);                            // lane^2 (quad_perm)
    { float t4a = DPPR(kv,0x124), t4b = DPPR(kv,0x12C);  // lane^4 via ror4/ror12
      kv *= (j4 ? t4a : t4b); }
    kv *= DPPR(kv,0x128);                           // lane^8 (ror:8 == xor8)
    float wk = fabsf(kv);
    float wkA = wk * preA;
    float wkB = wk * 0.5f;

    // cumprod via DPP1: shr:2/4/8 edge-invalid lanes (j<1 / j<2 / j<4)
    // keep old=1.0 -- exactly the old masks, zero cndmask cost.
#define CUMQ(ZV, WKX, GQ) { \
    float zz = (ZV); \
    float pz = zz; \
    pz *= DPP1(pz,0x112); \
    pz *= DPP1(pz,0x114); \
    pz *= DPP1(pz,0x118); \
    float q = (j==0)? 1.0f : zz; \
    q *= DPPR(q,0x4E); \
    { float q4a = DPPR(q,0x124), q4b = DPPR(q,0x12C); q *= (j4 ? q4a : q4b); } \
    q *= DPPR(q,0x128); \
    GQ = ((j==0)? q : pz) * (WKX); }

    float yA, yB;
    CUMQ(fcosrev(aA + xA), wkA, yA)
    CUMQ(fcosrev(aB + xB), wkB, yB)
#undef CUMQ

    // packed tanh13 core on pre-scaled inputs; act = postM*t + postB
    f2 y = {yA, yB};
    f2 s2 = y * y;
    f2 p = s2*C6 + C5;
    p = p*s2 + C4;
    p = p*s2 + C3;
    p = p*s2 + C2;
    p = p*s2 + C1;
    p = p*s2 + C0;
    f2 t2 = y * p;
    f2 act = t2*postMP + postBP;
    float actA = act.x, actB = act.y;

    // cross-pair gather: partner pb = lane^1 (quad_perm xor1)
    float gAo = DPPR(actA,0xB1);
    float gBo = DPPR(actB,0xB1);
    float fv = pb ? gAo  : actA;
    float uv = pb ? actA : gAo;
    float iv = pb ? gBo  : actB;
    float ov = pb ? actB : gBo;

    c = fmaf(fv, c, iv*uv);
    float c2 = c * c;
    float num = fmaf(c2, c2 + 105.0f, 945.0f);
    float den = fmaf(c2, fmaf(c2, 15.0f, 420.0f), 945.0f);
    float tch = c * num * frcp(den);
    h = ov * tch;

    // unconditional store: pb pair lanes write same addr, same value
    out[osto] = h;
    osto += BB*8;
  };

  for (int k = 0; k < 16; ++k){
    if (wid == 0){
      const float* baseA = &xp[k%3][0][0][0];
      const float* baseB = &xp[(k+1)%3][0][0][0];   // k=15: dead loads, safe
      // steps 0..27: prefetch from current chunk
#pragma unroll 1
      for (int s4 = 0; s4 < 28; s4 += 4){
        const float* bp4 = baseA + (s4+4)*160;
#pragma unroll
        for (int u = 0; u < 4; ++u) STEP(bp4 + u*160, u);
      }
      // steps 28..31: prefetch rows 0..3 of next chunk
#pragma unroll
      for (int u = 0; u < 4; ++u) STEP(baseB + u*160, u);
    } else if (wid == 1 || wid == 2){
      if (k + 2 < 16) produce(k + 2);
    }
    __syncthreads();
  }

  if (wid == 0){
    out[(size_t)TT*BB*8 + (size_t)(b0+bl)*8 + j] = h;
    out[(size_t)TT*BB*8 + (size_t)BB*8 + (size_t)(b0+bl)*8 + j] = c;
  }
}

extern "C" void kernel_launch(void* const* d_in, const int* in_sizes, int n_in,
                              void* d_out, int out_size, void* d_ws, size_t ws_size,
                              hipStream_t stream)
{
  const float* x    = (const float*)d_in[0];
  const float* Wf   = (const float*)d_in[1];
  const float* bf   = (const float*)d_in[2];
  const float* thf  = (const float*)d_in[3];
  const float* Wi   = (const float*)d_in[4];
  const float* bi   = (const float*)d_in[5];
  const float* thi  = (const float*)d_in[6];
  const float* Wu   = (const float*)d_in[7];
  const float* bu   = (const float*)d_in[8];
  const float* thu  = (const float*)d_in[9];
  const float* Wo   = (const float*)d_in[10];
  const float* bo   = (const float*)d_in[11];
  const float* tho  = (const float*)d_in[12];
  const float* Wh2k = (const float*)d_in[13];
  const float* bh2k = (const float*)d_in[14];
  const float* Wi2k = (const float*)d_in[15];
  const float* bi2k = (const float*)d_in[16];
  float* out = (float*)d_out;
  float* gw  = (float*)d_ws;           // [64][40] pre-scaled weights
  (void)ws_size; (void)in_sizes; (void)n_in; (void)out_size;

  qlstm_prep<<<10, 256, 0, stream>>>(Wf, Wi, Wu, Wo, Wi2k, gw);
  qlstm_fused<<<BB/4, 256, 0, stream>>>(
      x, gw, Wf,bf,thf, Wi,bi,thi, Wu,bu,thu, Wo,bo,tho,
      Wh2k, bh2k, Wi2k, bi2k, out);
}

// Round 18
// 153.703 us; speedup vs baseline: 2.6898x; 1.0594x over previous
//
#include <hip/hip_runtime.h>

#define TT 512
#define BB 1024
#define INV2PI 0.15915494309189535f
#define INV4PI 0.07957747154594767f

typedef __attribute__((ext_vector_type(2))) float f2;

__device__ __forceinline__ float frcp(float x){ return __builtin_amdgcn_rcpf(x); }
// cos(2*pi*r): v_fract_f32 (single-op range reduction) + V_COS
__device__ __forceinline__ float fcosrev(float r){
  return __builtin_amdgcn_cosf(__builtin_amdgcn_fractf(r));
}

#define DPPR(v, ctrl) __int_as_float(__builtin_amdgcn_update_dpp(__float_as_int(v), __float_as_int(v), (ctrl), 0xF, 0xF, false))
// row_shr with old=1.0 for lanes whose source falls off the 16-row edge.
// VALID ONLY when group boundaries coincide with row boundaries (interleaved
// pb layout: j-group = stride-2 lanes, so shr:2/4/8 invalid sets == mask sets).
#define DPP1(v, ctrl) __int_as_float(__builtin_amdgcn_update_dpp(0x3f800000, __float_as_int(v), (ctrl), 0xF, 0xF, false))

// INTERLEAVED lane mapping (R17): lane l: pb = l&1, j = (l>>1)&7.
// Column layout of a 40-float xpre row: c in [0,32): pairIdx = c>>1 = 2*j+pb,
// slot = c&1, gate g = 2*pb+slot (pb=0:{f,i}, pb=1:{u,o});
// value = (x@Wg[:64]+bg+thg)*INV2PI.  c in [32,40): unit j=c-32,
// value = (x@Wi2k+bi2k-bh2k)*INV4PI.

// Prep: pre-scaled weight matrix [64][40] into d_ws (global). Producers read
// it with wave-uniform indices -> scalar pipe (s_load), zero DS pressure.
__global__ __launch_bounds__(256,1) void qlstm_prep(
    const float* __restrict__ Wf, const float* __restrict__ Wi,
    const float* __restrict__ Wu, const float* __restrict__ Wo,
    const float* __restrict__ Wi2k,
    float* __restrict__ gw)
{
  int idx = blockIdx.x*256 + threadIdx.x;
  if (idx >= 64*40) return;
  int d = idx / 40, cc = idx - d*40;
  float v;
  if (cc < 32){
    int pi = cc >> 1, slot = cc & 1;
    int jj = pi >> 1, pbc = pi & 1;          // interleaved decode
    int g = 2*pbc + slot;
    const float* W = (g==0)?Wf:((g==1)?Wi:((g==2)?Wu:Wo));
    v = W[d*8+jj] * INV2PI;
  } else {
    v = Wi2k[d*8 + (cc-32)] * INV4PI;
  }
  gw[idx] = v;
}

// Fused: wave 0 scans 4 elements; waves 1-2 project 32-step chunks into
// triple-buffered LDS (weights via scalar pipe), 2 chunks ahead; wave 3
// barrier-only.
__global__ __launch_bounds__(256,1) void qlstm_fused(
    const float* __restrict__ x,
    const float* __restrict__ gw,
    const float* __restrict__ Wf, const float* __restrict__ bfp, const float* __restrict__ thf,
    const float* __restrict__ Wi, const float* __restrict__ bip, const float* __restrict__ thi,
    const float* __restrict__ Wu, const float* __restrict__ bup, const float* __restrict__ thu,
    const float* __restrict__ Wo, const float* __restrict__ bop, const float* __restrict__ tho,
    const float* __restrict__ Wh2k, const float* __restrict__ bh2k,
    const float* __restrict__ Wi2k, const float* __restrict__ bi2k,
    float* __restrict__ out)
{
  __shared__ float bias[40];
  __shared__ float xp[3][32][4][40];   // [buf][t_local][b_local][col]

  int tid = threadIdx.x;
  int b0 = blockIdx.x * 4;

  // ---- fill bias LDS (interleaved decode) ----
  if (tid < 40){
    int cc = tid; float v;
    if (cc < 32){
      int pi = cc >> 1, slot = cc & 1;
      int jj = pi >> 1, pbc = pi & 1;
      int g = 2*pbc + slot;
      const float* bp = (g==0)?bfp:((g==1)?bip:((g==2)?bup:bop));
      const float* tp = (g==0)?thf:((g==1)?thi:((g==2)?thu:tho));
      v = (bp[jj] + tp[jj]) * INV2PI;
    } else {
      v = (bi2k[cc-32] - bh2k[cc-32]) * INV4PI;
    }
    bias[cc] = v;
  }

  int wid = tid >> 6;
  bool pb = (tid & 1) != 0;            // interleaved: pb = bit0
  int j  = (tid >> 1) & 7;             // unit = bits1-3
  int bl = (tid >> 4) & 3;

  // producer lane mapping (waves 1-2) — unchanged
  int plane = tid - 64;                // 0..127
  int ptl = plane >> 2, pbl = plane & 3;

  auto produce = [&](int ck){
    int t = ck*32 + ptl;
    const float4* xr = (const float4*)(x + ((size_t)t*BB + b0 + pbl)*64);
    float4 acc[10];
    const float4* b4 = (const float4*)bias;
#pragma unroll
    for (int q=0;q<10;++q) acc[q] = b4[q];
#pragma unroll 1
    for (int k4=0;k4<16;++k4){
      float4 xv = xr[k4];
#pragma unroll
      for (int dd=0; dd<4; ++dd){
        float s = (dd==0)?xv.x:((dd==1)?xv.y:((dd==2)?xv.z:xv.w));
        // wave-uniform index -> scalar loads (s_load), not DS
        const float4* w4 = (const float4*)&gw[(k4*4+dd)*40];
#pragma unroll
        for (int q=0;q<10;++q){
          acc[q].x += s*w4[q].x; acc[q].y += s*w4[q].y;
          acc[q].z += s*w4[q].z; acc[q].w += s*w4[q].w;
        }
      }
    }
    float4* dst = (float4*)&xp[ck%3][ptl][pbl][0];
#pragma unroll
    for (int q=0;q<10;++q) dst[q] = acc[q];
  };

  // scan-wave recurrent weights, packed (even,odd) pairs
  const float* WA = pb ? Wu : Wf;
  const float* WB = pb ? Wo : Wi;
  float wsc[24];
#pragma unroll
  for (int s=0;s<8;++s){
    int k = (j + s) & 7;
    wsc[s]    = WA[(64+k)*8 + j] * INV2PI;
    wsc[8+s]  = WB[(64+k)*8 + j] * INV2PI;
    wsc[16+s] = Wh2k[k*8 + j] * INV4PI;
  }
  f2 wA01={wsc[0],wsc[1]},  wA23={wsc[2],wsc[3]},  wA45={wsc[4],wsc[5]},  wA67={wsc[6],wsc[7]};
  f2 wB01={wsc[8],wsc[9]},  wB23={wsc[10],wsc[11]},wB45={wsc[12],wsc[13]},wB67={wsc[14],wsc[15]};
  f2 wK01={wsc[16],wsc[17]},wK23={wsc[18],wsc[19]},wK45={wsc[20],wsc[21]},wK67={wsc[22],wsc[23]};

  float preA = pb ? 1.0f : 0.5f;       // folded tanh-core input scale (slot A)
  f2 postMP= { pb ? 1.0f : 0.5f, 0.5f };
  f2 postBP= { pb ? 0.0f : 0.5f, 0.5f };
  const f2 C6 = {0.00359213f,0.00359213f};
  const f2 C5 = {-0.00886324f,-0.00886324f};
  const f2 C4 = {0.02186948f,0.02186948f};
  const f2 C3 = {-0.05396825f,-0.05396825f};
  const f2 C2 = {0.13333333f,0.13333333f};
  const f2 C1 = {-0.33333333f,-0.33333333f};
  const f2 C0 = {1.0f,1.0f};

  float h = 0.f, c = 0.f;

  __syncthreads();                     // B0: bias ready

  if (wid == 1 || wid == 2){
    produce(0);
    produce(1);
  }

  __syncthreads();                     // B1: chunks 0,1 ready

  int oAB = bl*40 + 2*(tid & 15);      // pairIdx = lane&15 = 2*j+pb
  int oK  = bl*40 + 32 + j;
  f2 xABq[4]; float xKq[4];
  int osto = (b0 + bl)*8 + j;

  if (wid == 0){
#pragma unroll
    for (int i=0;i<4;++i){
      const float* sp = &xp[0][i][0][0];
      xABq[i] = *(const f2*)&sp[oAB];
      xKq[i]  = sp[oK];
    }
  }

  // one scan step; pp = prefetch row base for step s+4
  auto STEP = [&](const float* __restrict__ pp, int u){
    float xA = xABq[u].x, xB = xABq[u].y, xK = xKq[u];
    xABq[u] = *(const f2*)&pp[oAB];
    xKq[u]  = pp[oK];

    // rotations: lane l needs h[(j+s)&7] = lane (l+2s)&15 -> ror:(16-2s)
    float hr1 = DPPR(h,0x12E), hr2 = DPPR(h,0x12C), hr3 = DPPR(h,0x12A),
          hr4 = DPPR(h,0x128), hr5 = DPPR(h,0x126), hr6 = DPPR(h,0x124),
          hr7 = DPPR(h,0x122);
    f2 hp0 = {h, hr1}, hp1 = {hr2, hr3}, hp2 = {hr4, hr5}, hp3 = {hr6, hr7};

    f2 accA = hp0*wA01; accA = hp1*wA23 + accA; accA = hp2*wA45 + accA; accA = hp3*wA67 + accA;
    f2 accB = hp0*wB01; accB = hp1*wB23 + accB; accB = hp2*wB45 + accB; accB = hp3*wB67 + accB;
    f2 accK = hp0*wK01; accK = hp1*wK23 + accK; accK = hp2*wK45 + accK; accK = hp3*wK67 + accK;
    float aA = accA.x + accA.y;
    float aB = accB.x + accB.y;
    float aK = accK.x + accK.y;

    // kv: full product over the stride-2 j-group via ROTATION all-reduce
    // (full products need no xor pairing: x(l+2), x(l+4), x(l+8) of the
    // running product covers all 8 class members on every lane)
    float kv = fcosrev(aK - xK);
    kv *= DPPR(kv,0x12E);                           // x prod at l+2
    kv *= DPPR(kv,0x12C);                           // x prod at l+4
    kv *= DPPR(kv,0x128);                           // x prod at l+8
    float wk = fabsf(kv);
    float wkA = wk * preA;
    float wkB = wk * 0.5f;

    // cumprod via DPP1 (prefix, masks via old=1.0 row-edge semantics);
    // q = full product of (j==0?1:z) via rotation all-reduce.
#define CUMQ(ZV, WKX, GQ) { \
    float zz = (ZV); \
    float pz = zz; \
    pz *= DPP1(pz,0x112); \
    pz *= DPP1(pz,0x114); \
    pz *= DPP1(pz,0x118); \
    float q = (j==0)? 1.0f : zz; \
    q *= DPPR(q,0x12E); \
    q *= DPPR(q,0x12C); \
    q *= DPPR(q,0x128); \
    GQ = ((j==0)? q : pz) * (WKX); }

    float yA, yB;
    CUMQ(fcosrev(aA + xA), wkA, yA)
    CUMQ(fcosrev(aB + xB), wkB, yB)
#undef CUMQ

    // packed tanh13 core on pre-scaled inputs; act = postM*t + postB
    f2 y = {yA, yB};
    f2 s2 = y * y;
    f2 p = s2*C6 + C5;
    p = p*s2 + C4;
    p = p*s2 + C3;
    p = p*s2 + C2;
    p = p*s2 + C1;
    p = p*s2 + C0;
    f2 t2 = y * p;
    f2 act = t2*postMP + postBP;
    float actA = act.x, actB = act.y;

    // cross-pair gather: partner pb = lane^1 (quad_perm xor1)
    float gAo = DPPR(actA,0xB1);
    float gBo = DPPR(actB,0xB1);
    float fv = pb ? gAo  : actA;
    float uv = pb ? actA : gAo;
    float iv = pb ? gBo  : actB;
    float ov = pb ? actB : gBo;

    c = fmaf(fv, c, iv*uv);
    float c2 = c * c;
    float num = fmaf(c2, c2 + 105.0f, 945.0f);
    float den = fmaf(c2, fmaf(c2, 15.0f, 420.0f), 945.0f);
    float tch = c * num * frcp(den);
    h = ov * tch;

    // unconditional store: pb pair lanes write same addr, same value
    out[osto] = h;
    osto += BB*8;
  };

  for (int k = 0; k < 16; ++k){
    if (wid == 0){
      const float* baseA = &xp[k%3][0][0][0];
      const float* baseB = &xp[(k+1)%3][0][0][0];   // k=15: dead loads, safe
      // steps 0..27: prefetch from current chunk
#pragma unroll 1
      for (int s4 = 0; s4 < 28; s4 += 4){
        const float* bp4 = baseA + (s4+4)*160;
#pragma unroll
        for (int u = 0; u < 4; ++u) STEP(bp4 + u*160, u);
      }
      // steps 28..31: prefetch rows 0..3 of next chunk
#pragma unroll
      for (int u = 0; u < 4; ++u) STEP(baseB + u*160, u);
    } else if (wid == 1 || wid == 2){
      if (k + 2 < 16) produce(k + 2);
    }
    __syncthreads();
  }

  if (wid == 0){
    out[(size_t)TT*BB*8 + (size_t)(b0+bl)*8 + j] = h;
    out[(size_t)TT*BB*8 + (size_t)BB*8 + (size_t)(b0+bl)*8 + j] = c;
  }
}

extern "C" void kernel_launch(void* const* d_in, const int* in_sizes, int n_in,
                              void* d_out, int out_size, void* d_ws, size_t ws_size,
                              hipStream_t stream)
{
  const float* x    = (const float*)d_in[0];
  const float* Wf   = (const float*)d_in[1];
  const float* bf   = (const float*)d_in[2];
  const float* thf  = (const float*)d_in[3];
  const float* Wi   = (const float*)d_in[4];
  const float* bi   = (const float*)d_in[5];
  const float* thi  = (const float*)d_in[6];
  const float* Wu   = (const float*)d_in[7];
  const float* bu   = (const float*)d_in[8];
  const float* thu  = (const float*)d_in[9];
  const float* Wo   = (const float*)d_in[10];
  const float* bo   = (const float*)d_in[11];
  const float* tho  = (const float*)d_in[12];
  const float* Wh2k = (const float*)d_in[13];
  const float* bh2k = (const float*)d_in[14];
  const float* Wi2k = (const float*)d_in[15];
  const float* bi2k = (const float*)d_in[16];
  float* out = (float*)d_out;
  float* gw  = (float*)d_ws;           // [64][40] pre-scaled weights
  (void)ws_size; (void)in_sizes; (void)n_in; (void)out_size;

  qlstm_prep<<<10, 256, 0, stream>>>(Wf, Wi, Wu, Wo, Wi2k, gw);
  qlstm_fused<<<BB/4, 256, 0, stream>>>(
      x, gw, Wf,bf,thf, Wi,bi,thi, Wu,bu,thu, Wo,bo,tho,
      Wh2k, bh2k, Wi2k, bi2k, out);
}

// Round 19
// 150.110 us; speedup vs baseline: 2.7542x; 1.0239x over previous
//
#include <hip/hip_runtime.h>

#define TT 512
#define BB 1024
#define INV2PI 0.15915494309189535f
#define INV4PI 0.07957747154594767f

typedef __attribute__((ext_vector_type(2))) unsigned u2v;

__device__ __forceinline__ float frcp(float x){ return __builtin_amdgcn_rcpf(x); }
// cos(2*pi*r): v_fract_f32 (single-op range reduction) + V_COS
__device__ __forceinline__ float fcosrev(float r){
  return __builtin_amdgcn_cosf(__builtin_amdgcn_fractf(r));
}

#define DPPR(v, ctrl) __int_as_float(__builtin_amdgcn_update_dpp(__float_as_int(v), __float_as_int(v), (ctrl), 0xF, 0xF, false))
// row_shr with old=1.0 for row-edge-invalid lanes (stride-2 tree; R17/18-verified)
#define DPP1(v, ctrl) __int_as_float(__builtin_amdgcn_update_dpp(0x3f800000, __float_as_int(v), (ctrl), 0xF, 0xF, false))

// R19 lane mapping (scan waves 0 and 3): lane L: gl=L&1, j=(L>>1)&7,
// el=(L>>4)&1, gh=(L>>5). gate g = 2*gh+gl (0=f,1=i,2=u,3=o).
// xpre row (40 floats): c in [0,32): j=c>>2, g=c&3:
//   value = (x@Wg[:64]+bg+thg)*INV2PI. c in [32,40): unit j=c-32:
//   value = (x@Wi2k+bi2k-bh2k)*INV4PI.

// Prep: pre-scaled weight matrix [64][40] into d_ws (global). Producers read
// it with wave-uniform indices -> scalar pipe (s_load), zero DS pressure.
__global__ __launch_bounds__(256,1) void qlstm_prep(
    const float* __restrict__ Wf, const float* __restrict__ Wi,
    const float* __restrict__ Wu, const float* __restrict__ Wo,
    const float* __restrict__ Wi2k,
    float* __restrict__ gw)
{
  int idx = blockIdx.x*256 + threadIdx.x;
  if (idx >= 64*40) return;
  int d = idx / 40, cc = idx - d*40;
  float v;
  if (cc < 32){
    int jj = cc >> 2, g = cc & 3;            // R19 decode
    const float* W = (g==0)?Wf:((g==1)?Wi:((g==2)?Wu:Wo));
    v = W[d*8+jj] * INV2PI;
  } else {
    v = Wi2k[d*8 + (cc-32)] * INV4PI;
  }
  gw[idx] = v;
}

// Fused: waves 0 and 3 scan (2 elements each, 32 lanes/element, 1 gate/lane);
// waves 1-2 project 32-step chunks into triple-buffered LDS, 2 chunks ahead.
__global__ __launch_bounds__(256,1) void qlstm_fused(
    const float* __restrict__ x,
    const float* __restrict__ gw,
    const float* __restrict__ Wf, const float* __restrict__ bfp, const float* __restrict__ thf,
    const float* __restrict__ Wi, const float* __restrict__ bip, const float* __restrict__ thi,
    const float* __restrict__ Wu, const float* __restrict__ bup, const float* __restrict__ thu,
    const float* __restrict__ Wo, const float* __restrict__ bop, const float* __restrict__ tho,
    const float* __restrict__ Wh2k, const float* __restrict__ bh2k,
    const float* __restrict__ Wi2k, const float* __restrict__ bi2k,
    float* __restrict__ out)
{
  __shared__ float bias[40];
  __shared__ float xp[3][32][4][40];   // [buf][t_local][b_local][col]

  int tid = threadIdx.x;
  int b0 = blockIdx.x * 4;

  // ---- fill bias LDS (R19 decode) ----
  if (tid < 40){
    int cc = tid; float v;
    if (cc < 32){
      int jj = cc >> 2, g = cc & 3;
      const float* bp = (g==0)?bfp:((g==1)?bip:((g==2)?bup:bop));
      const float* tp = (g==0)?thf:((g==1)?thi:((g==2)?thu:tho));
      v = (bp[jj] + tp[jj]) * INV2PI;
    } else {
      v = (bi2k[cc-32] - bh2k[cc-32]) * INV4PI;
    }
    bias[cc] = v;
  }

  int wid = tid >> 6;
  int L  = tid & 63;
  int gl = L & 1;
  int j  = (L >> 1) & 7;
  int el = (L >> 4) & 1;
  bool hi = L >= 32;                   // gh bit (lane^32 partner via permlane)
  int g  = (hi ? 2 : 0) + gl;
  int elb = ((wid == 3) ? 2 : 0) + el; // element-in-block for scan waves
  bool isScan = (wid == 0) || (wid == 3);

  // producer lane mapping (waves 1-2) — unchanged from R15-R18
  int plane = tid - 64;                // 0..127
  int ptl = plane >> 2, pbl = plane & 3;

  auto produce = [&](int ck){
    int t = ck*32 + ptl;
    const float4* xr = (const float4*)(x + ((size_t)t*BB + b0 + pbl)*64);
    float4 acc[10];
    const float4* b4 = (const float4*)bias;
#pragma unroll
    for (int q=0;q<10;++q) acc[q] = b4[q];
#pragma unroll 1
    for (int k4=0;k4<16;++k4){
      float4 xv = xr[k4];
#pragma unroll
      for (int dd=0; dd<4; ++dd){
        float s = (dd==0)?xv.x:((dd==1)?xv.y:((dd==2)?xv.z:xv.w));
        // wave-uniform index -> scalar loads (s_load), not DS
        const float4* w4 = (const float4*)&gw[(k4*4+dd)*40];
#pragma unroll
        for (int q=0;q<10;++q){
          acc[q].x += s*w4[q].x; acc[q].y += s*w4[q].y;
          acc[q].z += s*w4[q].z; acc[q].w += s*w4[q].w;
        }
      }
    }
    float4* dst = (float4*)&xp[ck%3][ptl][pbl][0];
#pragma unroll
    for (int q=0;q<10;++q) dst[q] = acc[q];
  };

  // scan-wave recurrent weights: own gate column + full K column (rotated k)
  const float* Wg = (g==0)?Wf:((g==1)?Wi:((g==2)?Wu:Wo));
  float wG[8], wK[8];
#pragma unroll
  for (int s=0;s<8;++s){
    int k = (j + s) & 7;
    wG[s] = Wg[(64+k)*8 + j] * INV2PI;
    wK[s] = Wh2k[k*8 + j] * INV4PI;
  }
  float preG  = (g==2) ? 1.0f : 0.5f;  // tanh for u, sigmoid (x/2) otherwise
  float postM = (g==2) ? 1.0f : 0.5f;
  float postB = (g==2) ? 0.0f : 0.5f;

  float h = 0.f, c = 0.f;

  __syncthreads();                     // B0: bias ready

  if (wid == 1 || wid == 2){
    produce(0);
    produce(1);
  }

  __syncthreads();                     // B1: chunks 0,1 ready

  int oG = elb*40 + 4*j + g;
  int oK = elb*40 + 32 + j;
  float xGq[4], xKq[4];
  int osto = (b0 + elb)*8 + j;

  if (isScan){
#pragma unroll
    for (int i=0;i<4;++i){
      const float* sp = &xp[0][i>>2][0][0];  // careful: i is step, rows are [t][b]
      (void)sp;
    }
    // rows: xp[0][step][elb][col]
#pragma unroll
    for (int i=0;i<4;++i){
      const float* sp = &xp[0][i][0][0];
      xGq[i] = sp[oG];
      xKq[i] = sp[oK];
    }
  }

  // one scan step; pp = prefetch row base (t_local row) for step s+4
  auto STEP = [&](const float* __restrict__ pp, int u){
    float xG = xGq[u], xK = xKq[u];
    xGq[u] = pp[oG];
    xKq[u] = pp[oK];

    // rotations: lane needs h[(j+s)&7] = row-lane + 2s -> ror:(16-2s)
    float hr1 = DPPR(h,0x12E), hr2 = DPPR(h,0x12C), hr3 = DPPR(h,0x12A),
          hr4 = DPPR(h,0x128), hr5 = DPPR(h,0x126), hr6 = DPPR(h,0x124),
          hr7 = DPPR(h,0x122);

    // two scalar dots: own gate + K (K replicated across gl/gh)
    float aG =        h*wG[0];
    aG = fmaf(hr1,wG[1],aG); aG = fmaf(hr2,wG[2],aG); aG = fmaf(hr3,wG[3],aG);
    aG = fmaf(hr4,wG[4],aG); aG = fmaf(hr5,wG[5],aG); aG = fmaf(hr6,wG[6],aG);
    aG = fmaf(hr7,wG[7],aG);
    float aK =        h*wK[0];
    aK = fmaf(hr1,wK[1],aK); aK = fmaf(hr2,wK[2],aK); aK = fmaf(hr3,wK[3],aK);
    aK = fmaf(hr4,wK[4],aK); aK = fmaf(hr5,wK[5],aK); aK = fmaf(hr6,wK[6],aK);
    aK = fmaf(hr7,wK[7],aK);

    // kv: full product over j (stride-2 rotation all-reduce, R18-verified)
    float kv = fcosrev(aK - xK);
    kv *= DPPR(kv,0x12E);
    kv *= DPPR(kv,0x12C);
    kv *= DPPR(kv,0x128);
    float wkG = fabsf(kv) * preG;

    // own-gate qlayer: z, masked prefix (pz), full product ex-j0 (q)
    float zz = fcosrev(aG + xG);
    float pz = zz;
    pz *= DPP1(pz,0x112);
    pz *= DPP1(pz,0x114);
    pz *= DPP1(pz,0x118);
    float q = (j==0) ? 1.0f : zz;
    q *= DPPR(q,0x12E);
    q *= DPPR(q,0x12C);
    q *= DPPR(q,0x128);
    float y = ((j==0) ? q : pz) * wkG;

    // scalar tanh13 core; act = postM*t + postB
    float s2 = y*y;
    float p = fmaf(s2, 0.00359213f, -0.00886324f);
    p = fmaf(p, s2, 0.02186948f);
    p = fmaf(p, s2, -0.05396825f);
    p = fmaf(p, s2, 0.13333333f);
    p = fmaf(p, s2, -0.33333333f);
    p = fmaf(p, s2, 1.0f);
    float act = fmaf(y*p, postM, postB);

    // gather all 4 gates: xor1 (quad_perm) + lane^32 (permlane32_swap)
    float actX1 = DPPR(act, 0xB1);
    float p1 = gl ? actX1 : act;       // gate(0, gh)
    float p2 = gl ? act : actX1;       // gate(1, gh)
    u2v r1 = __builtin_amdgcn_permlane32_swap(__float_as_uint(p1), __float_as_uint(p1), false, false);
    u2v r2 = __builtin_amdgcn_permlane32_swap(__float_as_uint(p2), __float_as_uint(p2), false, false);
    float b0v = __uint_as_float(hi ? r1.x : r1.y);   // gate(0, gh^1)
    float b1v = __uint_as_float(hi ? r2.x : r2.y);   // gate(1, gh^1)
    float fv = hi ? b0v : p1;
    float iv = hi ? b1v : p2;
    float uv = hi ? p1 : b0v;
    float ov = hi ? p2 : b1v;

    c = fmaf(fv, c, iv*uv);
    float c2 = c * c;
    float num = fmaf(c2, c2 + 105.0f, 945.0f);
    float den = fmaf(c2, fmaf(c2, 15.0f, 420.0f), 945.0f);
    float tch = c * num * frcp(den);
    h = ov * tch;

    // unconditional store: all 4 dup lanes write same addr, same value
    out[osto] = h;
    osto += BB*8;
  };

  for (int k = 0; k < 16; ++k){
    if (isScan){
      const float* baseA = &xp[k%3][0][0][0];
      const float* baseB = &xp[(k+1)%3][0][0][0];   // k=15: dead loads, safe
      // steps 0..27: prefetch from current chunk
#pragma unroll 1
      for (int s4 = 0; s4 < 28; s4 += 4){
        const float* bp4 = baseA + (s4+4)*160;
#pragma unroll
        for (int u = 0; u < 4; ++u) STEP(bp4 + u*160, u);
      }
      // steps 28..31: prefetch rows 0..3 of next chunk
#pragma unroll
      for (int u = 0; u < 4; ++u) STEP(baseB + u*160, u);
    } else {
      if (k + 2 < 16) produce(k + 2);
    }
    __syncthreads();
  }

  if (isScan){
    out[(size_t)TT*BB*8 + (size_t)(b0+elb)*8 + j] = h;
    out[(size_t)TT*BB*8 + (size_t)BB*8 + (size_t)(b0+elb)*8 + j] = c;
  }
}

extern "C" void kernel_launch(void* const* d_in, const int* in_sizes, int n_in,
                              void* d_out, int out_size, void* d_ws, size_t ws_size,
                              hipStream_t stream)
{
  const float* x    = (const float*)d_in[0];
  const float* Wf   = (const float*)d_in[1];
  const float* bf   = (const float*)d_in[2];
  const float* thf  = (const float*)d_in[3];
  const float* Wi   = (const float*)d_in[4];
  const float* bi   = (const float*)d_in[5];
  const float* thi  = (const float*)d_in[6];
  const float* Wu   = (const float*)d_in[7];
  const float* bu   = (const float*)d_in[8];
  const float* thu  = (const float*)d_in[9];
  const float* Wo   = (const float*)d_in[10];
  const float* bo   = (const float*)d_in[11];
  const float* tho  = (const float*)d_in[12];
  const float* Wh2k = (const float*)d_in[13];
  const float* bh2k = (const float*)d_in[14];
  const float* Wi2k = (const float*)d_in[15];
  const float* bi2k = (const float*)d_in[16];
  float* out = (float*)d_out;
  float* gw  = (float*)d_ws;           // [64][40] pre-scaled weights
  (void)ws_size; (void)in_sizes; (void)n_in; (void)out_size;

  qlstm_prep<<<10, 256, 0, stream>>>(Wf, Wi, Wu, Wo, Wi2k, gw);
  qlstm_fused<<<BB/4, 256, 0, stream>>>(
      x, gw, Wf,bf,thf, Wi,bi,thi, Wu,bu,thu, Wo,bo,tho,
      Wh2k, bh2k, Wi2k, bi2k, out);
}